// Round 7
// baseline (17296.777 us; speedup 1.0000x reference)
//
#include <hip/hip_runtime.h>
#include <stdint.h>

// ---------------------------------------------------------------------------
// DecoderLSTM: B=32, S=128, H=1024, L=2, V=32000, teacher forcing (tf=1)
//
// ROUND 7 = MEASUREMENT ROUND. Real pipeline byte-identical to round 6
// (passed, persist=2166us). Added two probe kernels between persist and the
// proj GEMM (which overwrites all of d_out afterwards, so probes cannot
// affect validated output):
//   probe_sync_k: round-6 sync protocol only, 768 iters (6x)  -> dur = 6*S
//   probe_comp_k: round-6 compute/data path only, 768 iters    -> dur = 6*C
// Reading the top-5 table next round tells whether the 17us/iter floor is
// sync-latency (S) or data-path (C).
// ---------------------------------------------------------------------------

typedef __attribute__((ext_vector_type(8))) short short8;
typedef __attribute__((ext_vector_type(4))) float f32x4;

#define MFMA16(a, b, c) __builtin_amdgcn_mfma_f32_16x16x32_bf16((a), (b), (c), 0, 0, 0)

__device__ __forceinline__ unsigned short f2bf(float f) {
  union { float f; unsigned int u; } v; v.f = f;
  unsigned int u = v.u;
  return (unsigned short)((u + 0x7fffu + ((u >> 16) & 1u)) >> 16);
}

// device-coherent (sc1) primitives: relaxed AGENT atomics.
__device__ __forceinline__ void st_u32_dev(unsigned* p, unsigned v) {
  __hip_atomic_store(p, v, __ATOMIC_RELAXED, __HIP_MEMORY_SCOPE_AGENT);
}
__device__ __forceinline__ short8 ld16_dev(const unsigned short* p) {
  union { unsigned long long q[2]; short8 v; } r;
  const unsigned long long* pp = (const unsigned long long*)p;
  r.q[0] = __hip_atomic_load(pp, __ATOMIC_RELAXED, __HIP_MEMORY_SCOPE_AGENT);
  r.q[1] = __hip_atomic_load(pp + 1, __ATOMIC_RELAXED, __HIP_MEMORY_SCOPE_AGENT);
  return r.v;
}
__device__ __forceinline__ void poll_ge(unsigned* c, unsigned tgt) {
  while (__hip_atomic_load(c, __ATOMIC_RELAXED, __HIP_MEMORY_SCOPE_AGENT) < tgt)
    __builtin_amdgcn_s_sleep(1);
}
__device__ __forceinline__ void arrive(unsigned* c) {
  __hip_atomic_fetch_add(c, 1u, __ATOMIC_RELAXED, __HIP_MEMORY_SCOPE_AGENT);
}

// ---- conversion / small kernels -------------------------------------------

__global__ void cvt_bf16_k(const float* __restrict__ s, unsigned short* __restrict__ d, int n4) {
  int i = blockIdx.x * blockDim.x + threadIdx.x;
  int st = gridDim.x * blockDim.x;
  for (; i < n4; i += st) {
    float4 v = ((const float4*)s)[i];
    ushort4 o;
    o.x = f2bf(v.x); o.y = f2bf(v.y); o.z = f2bf(v.z); o.w = f2bf(v.w);
    ((ushort4*)d)[i] = o;
  }
}

__global__ void bias_sum_k(const float* __restrict__ a, const float* __restrict__ b,
                           float* __restrict__ o, int n) {
  int i = blockIdx.x * blockDim.x + threadIdx.x;
  if (i < n) o[i] = a[i] + b[i];
}

__global__ void embed_k(const int* __restrict__ x, const int* __restrict__ tgt,
                        const float* __restrict__ emb, unsigned short* __restrict__ xseq) {
  int row = blockIdx.x;          // t*32 + b
  int t = row >> 5, b = row & 31;
  int tok = (t == 0) ? x[b] : tgt[b * 128 + t];
  const float4* e = (const float4*)(emb + (size_t)tok * 1024);
  ushort4* o = (ushort4*)(xseq + (size_t)row * 1024);
  int i = threadIdx.x;
  float4 v = e[i];
  ushort4 u;
  u.x = f2bf(v.x); u.y = f2bf(v.y); u.z = f2bf(v.z); u.w = f2bf(v.w);
  o[i] = u;
}

// ---- bf16 MFMA GEMM: C[M][N] = A[M][K] * B[N][K]^T (+bias[col]) -----------

__global__ __launch_bounds__(256, 2) void gemm_bf16_k(
    const unsigned short* __restrict__ A, const unsigned short* __restrict__ B,
    float* __restrict__ C, const float* __restrict__ bias, int N) {
  __shared__ __align__(16) unsigned short As[128 * 64];
  __shared__ __align__(16) unsigned short Bs[128 * 64];
  const int tid = threadIdx.x;
  const int lane = tid & 63;
  const int w = tid >> 6;
  const int wm = w >> 1, wn = w & 1;
  const int mBase = blockIdx.y * 128;
  const int nBase = blockIdx.x * 128;
  const int lr = lane & 15, lk = lane >> 4;
  const int K = 1024;

  f32x4 acc[4][4];
#pragma unroll
  for (int i = 0; i < 4; ++i)
#pragma unroll
    for (int j = 0; j < 4; ++j) acc[i][j] = (f32x4){0.f, 0.f, 0.f, 0.f};

  for (int kt = 0; kt < K / 64; ++kt) {
    int4 va[4], vb[4];
#pragma unroll
    for (int r = 0; r < 4; ++r) {
      int q = r * 256 + tid;
      int row = q >> 3, c = q & 7;
      va[r] = *(const int4*)(A + (size_t)(mBase + row) * K + kt * 64 + c * 8);
      vb[r] = *(const int4*)(B + (size_t)(nBase + row) * K + kt * 64 + c * 8);
    }
    __syncthreads();
#pragma unroll
    for (int r = 0; r < 4; ++r) {
      int q = r * 256 + tid;
      int row = q >> 3, c = q & 7;
      int cs = c ^ (row & 7);
      *(int4*)&As[row * 64 + cs * 8] = va[r];
      *(int4*)&Bs[row * 64 + cs * 8] = vb[r];
    }
    __syncthreads();
#pragma unroll
    for (int ks = 0; ks < 2; ++ks) {
      short8 a[4], b[4];
#pragma unroll
      for (int mf = 0; mf < 4; ++mf) {
        int row = wm * 64 + mf * 16 + lr;
        int cc = (ks * 4 + lk) ^ (row & 7);
        a[mf] = *(const short8*)&As[row * 64 + cc * 8];
      }
#pragma unroll
      for (int nf = 0; nf < 4; ++nf) {
        int row = wn * 64 + nf * 16 + lr;
        int cc = (ks * 4 + lk) ^ (row & 7);
        b[nf] = *(const short8*)&Bs[row * 64 + cc * 8];
      }
#pragma unroll
      for (int mf = 0; mf < 4; ++mf)
#pragma unroll
        for (int nf = 0; nf < 4; ++nf)
          acc[mf][nf] = MFMA16(a[mf], b[nf], acc[mf][nf]);
    }
  }

#pragma unroll
  for (int mf = 0; mf < 4; ++mf) {
#pragma unroll
    for (int nf = 0; nf < 4; ++nf) {
      int col = nBase + wn * 64 + nf * 16 + lr;
      float bv = bias ? bias[col] : 0.f;
#pragma unroll
      for (int i = 0; i < 4; ++i) {
        int row = mBase + wm * 64 + mf * 16 + lk * 4 + i;
        C[(size_t)row * N + col] = acc[mf][nf][i] + bv;
      }
    }
  }
}

// ---- persistent recurrence kernel (IDENTICAL to round 6) ------------------

struct PParams {
  const float* zx0;
  const unsigned short* whh0;
  const unsigned short* wih1;
  const unsigned short* whh1;
  const float* bsum1;
  const float* cell;
  unsigned short* h0hist;
  const unsigned short* h1init;
  unsigned short* outb;
  unsigned int* arr0;
  unsigned int* arr1;
};

__global__ __launch_bounds__(256, 1) void lstm_persist_k(PParams P) {
  const int tid = threadIdx.x;
  const int lane = tid & 63;
  const int w = tid >> 6;
  const int lr = lane & 15, lkk = lane >> 4;

  __shared__ __align__(16) unsigned short wlds[65536];
  __shared__ float zbuf[32][68];

  if (blockIdx.x < 64) {
    const int u0 = blockIdx.x * 16;
    const int grp = blockIdx.x & 3;
    const int m = w >> 1;
    const int p = w & 1;
    const int g0 = p * 2, g1 = p * 2 + 1;

    for (int f = w; f < 128; f += 4) {
      int g = f >> 5, kc = f & 31;
      const unsigned short* src =
          P.whh0 + (size_t)(g * 1024 + u0 + lr) * 1024 + kc * 32 + lkk * 8;
      *(short8*)&wlds[f * 512 + lane * 8] = *(const short8*)src;
    }
    const int fb = tid >> 3;
    const int jp = tid & 7;
    float creg[2];
    creg[0] = P.cell[fb * 1024 + u0 + 2 * jp];
    creg[1] = P.cell[fb * 1024 + u0 + 2 * jp + 1];
    __syncthreads();

    for (int i = 0; i < 128; ++i) {
      if (i > 0 && tid < 4) poll_ge(&P.arr0[tid * 256], (unsigned)(16 * i));
      asm volatile("" ::: "memory");
      __syncthreads();

      float2 zr[4];
      {
        const float2* br = (const float2*)(P.zx0 + (size_t)i * 131072 + fb * 4096 + u0 + 2 * jp);
#pragma unroll
        for (int g = 0; g < 4; ++g) zr[g] = br[g * 512];
      }
      f32x4 acc0 = {0.f, 0.f, 0.f, 0.f}, acc1 = {0.f, 0.f, 0.f, 0.f};
      const unsigned short* ap =
          P.h0hist + (size_t)i * 32768 + (size_t)(m * 16 + lr) * 1024 + lkk * 8;
#pragma unroll
      for (int g4 = 0; g4 < 4; ++g4) {
        short8 a[8];
#pragma unroll
        for (int q = 0; q < 8; ++q) a[q] = ld16_dev(ap + (g4 * 8 + q) * 32);
#pragma unroll
        for (int q = 0; q < 8; ++q) {
          int kc = g4 * 8 + q;
          short8 b0 = *(const short8*)&wlds[(g0 * 32 + kc) * 512 + lane * 8];
          short8 b1 = *(const short8*)&wlds[(g1 * 32 + kc) * 512 + lane * 8];
          acc0 = MFMA16(a[q], b0, acc0);
          acc1 = MFMA16(a[q], b1, acc1);
        }
      }
#pragma unroll
      for (int j = 0; j < 4; ++j) {
        zbuf[m * 16 + lkk * 4 + j][g0 * 16 + lr] = acc0[j];
        zbuf[m * 16 + lkk * 4 + j][g1 * 16 + lr] = acc1[j];
      }
      __syncthreads();

      unsigned hv = 0;
#pragma unroll
      for (int u = 0; u < 2; ++u) {
        int j = 2 * jp + u;
        float zi = zbuf[fb][j]      + ((u == 0) ? zr[0].x : zr[0].y);
        float zf = zbuf[fb][16 + j] + ((u == 0) ? zr[1].x : zr[1].y);
        float zg = zbuf[fb][32 + j] + ((u == 0) ? zr[2].x : zr[2].y);
        float zo = zbuf[fb][48 + j] + ((u == 0) ? zr[3].x : zr[3].y);
        float ii = 1.f / (1.f + __expf(-zi));
        float ff = 1.f / (1.f + __expf(-zf));
        float gg = tanhf(zg);
        float oo = 1.f / (1.f + __expf(-zo));
        float cn = ff * creg[u] + ii * gg;
        creg[u] = cn;
        float hn = oo * tanhf(cn);
        hv |= ((unsigned)f2bf(hn)) << (16 * u);
      }
      st_u32_dev((unsigned*)&P.h0hist[(size_t)(i + 1) * 32768 + fb * 1024 + u0 + 2 * jp], hv);

      __syncthreads();
      if (tid == 0) arrive(&P.arr0[grp * 256]);
    }
  } else {
    const int u0 = (blockIdx.x - 64) * 8;
    const int grp = (blockIdx.x - 64) & 7;
    const int m = w >> 1;
    const int n = w & 1;

    for (int f = w; f < 128; f += 4) {
      int mat = f >> 6, nt = (f >> 5) & 1, kc = f & 31;
      int rr = nt * 16 + lr;
      int gate = rr >> 3, unit = rr & 7;
      const unsigned short* Wm = mat ? P.whh1 : P.wih1;
      const unsigned short* src =
          Wm + (size_t)(gate * 1024 + u0 + unit) * 1024 + kc * 32 + lkk * 8;
      *(short8*)&wlds[f * 512 + lane * 8] = *(const short8*)src;
    }
    const int fb = tid >> 2;
    const int jp = tid & 3;
    float creg[2] = {0.f, 0.f};
    float brg[4][2];
    if (tid < 128) {
      creg[0] = P.cell[32768 + fb * 1024 + u0 + 2 * jp];
      creg[1] = P.cell[32768 + fb * 1024 + u0 + 2 * jp + 1];
#pragma unroll
      for (int g = 0; g < 4; ++g) {
        brg[g][0] = P.bsum1[g * 1024 + u0 + 2 * jp];
        brg[g][1] = P.bsum1[g * 1024 + u0 + 2 * jp + 1];
      }
    }
    __syncthreads();

    for (int i = 1; i <= 128; ++i) {
      if (tid < 12) {
        if (tid < 4) poll_ge(&P.arr0[tid * 256], (unsigned)(16 * i));
        else if (i > 1) poll_ge(&P.arr1[(tid - 4) * 256], (unsigned)(16 * (i - 1)));
      }
      asm volatile("" ::: "memory");
      __syncthreads();

      f32x4 accA = {0.f, 0.f, 0.f, 0.f}, accB = {0.f, 0.f, 0.f, 0.f};
      const unsigned short* a0p =
          P.h0hist + (size_t)i * 32768 + (size_t)(m * 16 + lr) * 1024 + lkk * 8;
      size_t h1s = (i == 1) ? 1024 : 131072;
      const unsigned short* h1b =
          (i == 1) ? P.h1init : (P.outb + (size_t)(i - 2) * 1024);
      const unsigned short* a1p = h1b + (size_t)(m * 16 + lr) * h1s + lkk * 8;
#pragma unroll
      for (int g4 = 0; g4 < 4; ++g4) {
        short8 a0[8], a1[8];
#pragma unroll
        for (int q = 0; q < 8; ++q) {
          a0[q] = ld16_dev(a0p + (g4 * 8 + q) * 32);
          a1[q] = ld16_dev(a1p + (g4 * 8 + q) * 32);
        }
#pragma unroll
        for (int q = 0; q < 8; ++q) {
          int kc = g4 * 8 + q;
          short8 bi = *(const short8*)&wlds[(n * 32 + kc) * 512 + lane * 8];
          short8 bh = *(const short8*)&wlds[(64 + n * 32 + kc) * 512 + lane * 8];
          accA = MFMA16(a0[q], bi, accA);
          accB = MFMA16(a1[q], bh, accB);
        }
      }
      f32x4 acc = accA + accB;
#pragma unroll
      for (int j = 0; j < 4; ++j)
        zbuf[m * 16 + lkk * 4 + j][n * 16 + lr] = acc[j];
      __syncthreads();

      if (tid < 128) {
        unsigned hv = 0;
#pragma unroll
        for (int u = 0; u < 2; ++u) {
          int j = 2 * jp + u;
          float zi = zbuf[fb][j]      + brg[0][u];
          float zf = zbuf[fb][8 + j]  + brg[1][u];
          float zg = zbuf[fb][16 + j] + brg[2][u];
          float zo = zbuf[fb][24 + j] + brg[3][u];
          float ii = 1.f / (1.f + __expf(-zi));
          float ff = 1.f / (1.f + __expf(-zf));
          float gg = tanhf(zg);
          float oo = 1.f / (1.f + __expf(-zo));
          float cn = ff * creg[u] + ii * gg;
          creg[u] = cn;
          float hn = oo * tanhf(cn);
          hv |= ((unsigned)f2bf(hn)) << (16 * u);
        }
        st_u32_dev((unsigned*)&P.outb[(size_t)fb * 131072 + (size_t)(i - 1) * 1024 + u0 + 2 * jp], hv);
      }

      __syncthreads();
      if (tid == 0) arrive(&P.arr1[grp * 256]);
    }
  }
}

// ---- PROBE 1: sync protocol only, 6x iterations ---------------------------
// Own counter region; bounded poll budget (cannot hang). dur = 6 * S.

__global__ __launch_bounds__(256, 1) void probe_sync_k(unsigned* arr0p, unsigned* arr1p) {
  const int tid = threadIdx.x;
  long budget = 4000000;
  if (blockIdx.x < 64) {
    const int grp = blockIdx.x & 3;
    for (int it = 0; it < 768; ++it) {
      if (it > 0 && tid < 4) {
        unsigned tgt = 16u * (unsigned)it;
        while (__hip_atomic_load(&arr0p[tid * 256], __ATOMIC_RELAXED,
                                 __HIP_MEMORY_SCOPE_AGENT) < tgt && --budget > 0)
          __builtin_amdgcn_s_sleep(1);
      }
      asm volatile("" ::: "memory");
      __syncthreads();
      __syncthreads();
      if (tid == 0) arrive(&arr0p[grp * 256]);
    }
  } else {
    const int grp = (blockIdx.x - 64) & 7;
    for (int it = 1; it <= 768; ++it) {
      if (tid < 12) {
        if (tid < 4) {
          unsigned tgt = 16u * (unsigned)it;
          while (__hip_atomic_load(&arr0p[tid * 256], __ATOMIC_RELAXED,
                                   __HIP_MEMORY_SCOPE_AGENT) < tgt && --budget > 0)
            __builtin_amdgcn_s_sleep(1);
        } else if (it > 1) {
          unsigned tgt = 16u * (unsigned)(it - 1);
          while (__hip_atomic_load(&arr1p[(tid - 4) * 256], __ATOMIC_RELAXED,
                                   __HIP_MEMORY_SCOPE_AGENT) < tgt && --budget > 0)
            __builtin_amdgcn_s_sleep(1);
        }
      }
      asm volatile("" ::: "memory");
      __syncthreads();
      __syncthreads();
      if (tid == 0) arrive(&arr1p[grp * 256]);
    }
  }
}

// ---- PROBE 2: compute/data path only, 6x iterations, no cross-WG sync -----
// Reads the REAL h0hist/outb/zx0 (stable after persist); stores go to
// h0hist[1..128] (layer0, dead: proj overwrites d_out) and xseq (layer1,
// dead after Zx0 GEMM). dur = 6 * C.

__global__ __launch_bounds__(256, 1) void probe_comp_k(PParams P, unsigned short* dummy) {
  const int tid = threadIdx.x;
  const int lane = tid & 63;
  const int w = tid >> 6;
  const int lr = lane & 15, lkk = lane >> 4;

  __shared__ __align__(16) unsigned short wlds[65536];
  __shared__ float zbuf[32][68];

  if (blockIdx.x < 64) {
    const int u0 = blockIdx.x * 16;
    const int m = w >> 1;
    const int p = w & 1;
    const int g0 = p * 2, g1 = p * 2 + 1;
    for (int f = w; f < 128; f += 4) {
      int g = f >> 5, kc = f & 31;
      const unsigned short* src =
          P.whh0 + (size_t)(g * 1024 + u0 + lr) * 1024 + kc * 32 + lkk * 8;
      *(short8*)&wlds[f * 512 + lane * 8] = *(const short8*)src;
    }
    const int fb = tid >> 3;
    const int jp = tid & 7;
    float creg[2];
    creg[0] = P.cell[fb * 1024 + u0 + 2 * jp];
    creg[1] = P.cell[fb * 1024 + u0 + 2 * jp + 1];
    __syncthreads();

    for (int it = 0; it < 768; ++it) {
      int i = it & 127;
      float2 zr[4];
      {
        const float2* br = (const float2*)(P.zx0 + (size_t)i * 131072 + fb * 4096 + u0 + 2 * jp);
#pragma unroll
        for (int g = 0; g < 4; ++g) zr[g] = br[g * 512];
      }
      f32x4 acc0 = {0.f, 0.f, 0.f, 0.f}, acc1 = {0.f, 0.f, 0.f, 0.f};
      const unsigned short* ap =
          P.h0hist + (size_t)i * 32768 + (size_t)(m * 16 + lr) * 1024 + lkk * 8;
#pragma unroll
      for (int g4 = 0; g4 < 4; ++g4) {
        short8 a[8];
#pragma unroll
        for (int q = 0; q < 8; ++q) a[q] = ld16_dev(ap + (g4 * 8 + q) * 32);
#pragma unroll
        for (int q = 0; q < 8; ++q) {
          int kc = g4 * 8 + q;
          short8 b0 = *(const short8*)&wlds[(g0 * 32 + kc) * 512 + lane * 8];
          short8 b1 = *(const short8*)&wlds[(g1 * 32 + kc) * 512 + lane * 8];
          acc0 = MFMA16(a[q], b0, acc0);
          acc1 = MFMA16(a[q], b1, acc1);
        }
      }
#pragma unroll
      for (int j = 0; j < 4; ++j) {
        zbuf[m * 16 + lkk * 4 + j][g0 * 16 + lr] = acc0[j];
        zbuf[m * 16 + lkk * 4 + j][g1 * 16 + lr] = acc1[j];
      }
      __syncthreads();
      unsigned hv = 0;
#pragma unroll
      for (int u = 0; u < 2; ++u) {
        int j = 2 * jp + u;
        float zi = zbuf[fb][j]      + ((u == 0) ? zr[0].x : zr[0].y);
        float zf = zbuf[fb][16 + j] + ((u == 0) ? zr[1].x : zr[1].y);
        float zg = zbuf[fb][32 + j] + ((u == 0) ? zr[2].x : zr[2].y);
        float zo = zbuf[fb][48 + j] + ((u == 0) ? zr[3].x : zr[3].y);
        float ii = 1.f / (1.f + __expf(-zi));
        float ff = 1.f / (1.f + __expf(-zf));
        float gg = tanhf(zg);
        float oo = 1.f / (1.f + __expf(-zo));
        float cn = ff * creg[u] + ii * gg;
        creg[u] = cn;
        float hn = oo * tanhf(cn);
        hv |= ((unsigned)f2bf(hn)) << (16 * u);
      }
      st_u32_dev((unsigned*)&P.h0hist[(size_t)(i + 1) * 32768 + fb * 1024 + u0 + 2 * jp], hv);
      __syncthreads();
    }
  } else {
    const int u0 = (blockIdx.x - 64) * 8;
    const int m = w >> 1;
    const int n = w & 1;
    for (int f = w; f < 128; f += 4) {
      int mat = f >> 6, nt = (f >> 5) & 1, kc = f & 31;
      int rr = nt * 16 + lr;
      int gate = rr >> 3, unit = rr & 7;
      const unsigned short* Wm = mat ? P.whh1 : P.wih1;
      const unsigned short* src =
          Wm + (size_t)(gate * 1024 + u0 + unit) * 1024 + kc * 32 + lkk * 8;
      *(short8*)&wlds[f * 512 + lane * 8] = *(const short8*)src;
    }
    const int fb = tid >> 2;
    const int jp = tid & 3;
    float creg[2] = {0.f, 0.f};
    float brg[4][2];
    if (tid < 128) {
      creg[0] = P.cell[32768 + fb * 1024 + u0 + 2 * jp];
      creg[1] = P.cell[32768 + fb * 1024 + u0 + 2 * jp + 1];
#pragma unroll
      for (int g = 0; g < 4; ++g) {
        brg[g][0] = P.bsum1[g * 1024 + u0 + 2 * jp];
        brg[g][1] = P.bsum1[g * 1024 + u0 + 2 * jp + 1];
      }
    }
    __syncthreads();

    for (int it = 1; it <= 768; ++it) {
      int i = ((it - 1) & 127) + 1;
      f32x4 accA = {0.f, 0.f, 0.f, 0.f}, accB = {0.f, 0.f, 0.f, 0.f};
      const unsigned short* a0p =
          P.h0hist + (size_t)i * 32768 + (size_t)(m * 16 + lr) * 1024 + lkk * 8;
      size_t h1s = (i == 1) ? 1024 : 131072;
      const unsigned short* h1b =
          (i == 1) ? P.h1init : (P.outb + (size_t)(i - 2) * 1024);
      const unsigned short* a1p = h1b + (size_t)(m * 16 + lr) * h1s + lkk * 8;
#pragma unroll
      for (int g4 = 0; g4 < 4; ++g4) {
        short8 a0[8], a1[8];
#pragma unroll
        for (int q = 0; q < 8; ++q) {
          a0[q] = ld16_dev(a0p + (g4 * 8 + q) * 32);
          a1[q] = ld16_dev(a1p + (g4 * 8 + q) * 32);
        }
#pragma unroll
        for (int q = 0; q < 8; ++q) {
          int kc = g4 * 8 + q;
          short8 bi = *(const short8*)&wlds[(n * 32 + kc) * 512 + lane * 8];
          short8 bh = *(const short8*)&wlds[(64 + n * 32 + kc) * 512 + lane * 8];
          accA = MFMA16(a0[q], bi, accA);
          accB = MFMA16(a1[q], bh, accB);
        }
      }
      f32x4 acc = accA + accB;
#pragma unroll
      for (int j = 0; j < 4; ++j)
        zbuf[m * 16 + lkk * 4 + j][n * 16 + lr] = acc[j];
      __syncthreads();
      if (tid < 128) {
        unsigned hv = 0;
#pragma unroll
        for (int u = 0; u < 2; ++u) {
          int j = 2 * jp + u;
          float zi = zbuf[fb][j]      + brg[0][u];
          float zf = zbuf[fb][8 + j]  + brg[1][u];
          float zg = zbuf[fb][16 + j] + brg[2][u];
          float zo = zbuf[fb][24 + j] + brg[3][u];
          float ii = 1.f / (1.f + __expf(-zi));
          float ff = 1.f / (1.f + __expf(-zf));
          float gg = tanhf(zg);
          float oo = 1.f / (1.f + __expf(-zo));
          float cn = ff * creg[u] + ii * gg;
          creg[u] = cn;
          float hn = oo * tanhf(cn);
          hv |= ((unsigned)f2bf(hn)) << (16 * u);
        }
        st_u32_dev((unsigned*)&dummy[(size_t)fb * 131072 + (size_t)(i - 1) * 1024 + u0 + 2 * jp], hv);
      }
      __syncthreads();
    }
  }
}

// ---------------------------------------------------------------------------

extern "C" void kernel_launch(void* const* d_in, const int* in_sizes, int n_in,
                              void* d_out, int out_size, void* d_ws, size_t ws_size,
                              hipStream_t stream) {
  const int*   x      = (const int*)d_in[0];
  const float* hidden = (const float*)d_in[1];
  const float* cell   = (const float*)d_in[2];
  const int*   target = (const int*)d_in[3];
  const float* emb    = (const float*)d_in[5];
  const float* w_ih   = (const float*)d_in[6];
  const float* w_hh   = (const float*)d_in[7];
  const float* b_ih   = (const float*)d_in[8];
  const float* b_hh   = (const float*)d_in[9];
  float* out = (float*)d_out;
  char* ws = (char*)d_ws;

  // ws layout (bytes)
  unsigned short* emb_bf  = (unsigned short*)(ws);                 // 65,536,000
  unsigned short* wih0_bf = (unsigned short*)(ws + 65536000);      //  8,388,608
  unsigned short* whh_bf  = (unsigned short*)(ws + 73924608);      // 16,777,216
  unsigned short* wih1_bf = (unsigned short*)(ws + 90701824);      //  8,388,608
  float*          bsum    = (float*)(ws + 99090432);               //     32,768
  unsigned short* outb    = (unsigned short*)(ws + 99123200);      //  8,388,608
  unsigned int*   barmem  = (unsigned int*)(ws + 107511808);       //     32,768 (real + probe counters)
  // Large transients in d_out's dead space (proj GEMM overwrites last):
  float*          zx0    = (float*)((char*)d_out);                         // 67,108,864
  unsigned short* xseq   = (unsigned short*)((char*)d_out + 67108864);     //  8,388,608
  unsigned short* h0hist = (unsigned short*)((char*)d_out + 75497472);     //  8,454,144
  unsigned short* h1init = (unsigned short*)((char*)d_out + 83951616);     //     65,536

  hipMemsetAsync(barmem, 0, 32768, stream);
  cvt_bf16_k<<<2048, 256, 0, stream>>>(emb, emb_bf, 8192000);
  cvt_bf16_k<<<1024, 256, 0, stream>>>(w_ih, wih0_bf, 1048576);
  cvt_bf16_k<<<2048, 256, 0, stream>>>(w_hh, whh_bf, 2097152);
  cvt_bf16_k<<<1024, 256, 0, stream>>>(w_ih + 4194304, wih1_bf, 1048576);
  cvt_bf16_k<<<32, 256, 0, stream>>>(hidden, h0hist, 8192);          // h0hist[0]
  cvt_bf16_k<<<32, 256, 0, stream>>>(hidden + 32768, h1init, 8192);
  bias_sum_k<<<32, 256, 0, stream>>>(b_ih, b_hh, bsum, 8192);
  embed_k<<<4096, 256, 0, stream>>>(x, target, emb, xseq);

  // Zx0 = x_seq @ w_ih[0]^T + bsum0   [4096 x 4096]
  gemm_bf16_k<<<dim3(32, 32), 256, 0, stream>>>(xseq, wih0_bf, zx0, bsum, 4096);

  // persistent recurrence (identical to round 6)
  PParams pp;
  pp.zx0 = zx0;
  pp.whh0 = whh_bf;
  pp.wih1 = wih1_bf;
  pp.whh1 = whh_bf + 4194304;
  pp.bsum1 = bsum + 4096;
  pp.cell = cell;
  pp.h0hist = h0hist;
  pp.h1init = h1init;
  pp.outb = outb;
  pp.arr0 = barmem;                // 4 counters, 1KB apart
  pp.arr1 = barmem + 4 * 256;      // 8 counters, 1KB apart
  lstm_persist_k<<<192, 256, 0, stream>>>(pp);

  // --- probes (outputs all dead; d_out fully overwritten by proj below) ---
  probe_sync_k<<<192, 256, 0, stream>>>(barmem + 4096, barmem + 4096 + 1024);
  probe_comp_k<<<192, 256, 0, stream>>>(pp, xseq);

  // out = outb @ emb_bf^T   [4096 x 32000]
  gemm_bf16_k<<<dim3(250, 32), 256, 0, stream>>>(outb, emb_bf, out, nullptr, 32000);
}

// Round 8
// 3432.534 us; speedup vs baseline: 5.0391x; 5.0391x over previous
//
#include <hip/hip_runtime.h>
#include <stdint.h>

// ---------------------------------------------------------------------------
// DecoderLSTM: B=32, S=128, H=1024, L=2, V=32000, teacher forcing (tf=1)
//
//   1. cvt weights/emb -> bf16, bsum = b_ih+b_hh, h/c inits.
//   2. embed tokens -> x_seq bf16 [4096][1024] (rows t*32+b)     (in d_out)
//   3. Zx0 = x_seq @ w_ih[0]^T + bsum0  (MFMA GEMM, f32)         (in d_out)
//   4. ONE persistent kernel. Weights in LDS (128 KB/WG). Producer/consumer
//      counters. h communicated via: sc1 WRITE-THROUGH stores (producer) +
//      CACHEABLE short8 loads after a per-iter thread0 __threadfence()
//      (wbl2+inv) on the consumer (round-4 protocol). Round-7 ablation:
//      data path w/ sc1 uncached loads was 15.7us/iter (L3-BW bound on
//      40 MB/iter redundant reads); sync was ~1us. Cacheable reads let the
//      16 WGs/XCD share one L2 fill -> ~1.6 MB/iter through L3.
//   5. out = outb @ emb_bf^T (MFMA GEMM, M=4096, N=32000, K=1024)
// ---------------------------------------------------------------------------

typedef __attribute__((ext_vector_type(8))) short short8;
typedef __attribute__((ext_vector_type(4))) float f32x4;

#define MFMA16(a, b, c) __builtin_amdgcn_mfma_f32_16x16x32_bf16((a), (b), (c), 0, 0, 0)

__device__ __forceinline__ unsigned short f2bf(float f) {
  union { float f; unsigned int u; } v; v.f = f;
  unsigned int u = v.u;
  return (unsigned short)((u + 0x7fffu + ((u >> 16) & 1u)) >> 16);
}

// producer stores: sc1 write-through (device-visible once vmcnt-drained)
__device__ __forceinline__ void st_u32_dev(unsigned* p, unsigned v) {
  __hip_atomic_store(p, v, __ATOMIC_RELAXED, __HIP_MEMORY_SCOPE_AGENT);
}
__device__ __forceinline__ void poll_ge(unsigned* c, unsigned tgt) {
  while (__hip_atomic_load(c, __ATOMIC_RELAXED, __HIP_MEMORY_SCOPE_AGENT) < tgt)
    __builtin_amdgcn_s_sleep(1);
}
__device__ __forceinline__ void arrive(unsigned* c) {
  __hip_atomic_fetch_add(c, 1u, __ATOMIC_RELAXED, __HIP_MEMORY_SCOPE_AGENT);
}

// ---- conversion / small kernels -------------------------------------------

__global__ void cvt_bf16_k(const float* __restrict__ s, unsigned short* __restrict__ d, int n4) {
  int i = blockIdx.x * blockDim.x + threadIdx.x;
  int st = gridDim.x * blockDim.x;
  for (; i < n4; i += st) {
    float4 v = ((const float4*)s)[i];
    ushort4 o;
    o.x = f2bf(v.x); o.y = f2bf(v.y); o.z = f2bf(v.z); o.w = f2bf(v.w);
    ((ushort4*)d)[i] = o;
  }
}

__global__ void bias_sum_k(const float* __restrict__ a, const float* __restrict__ b,
                           float* __restrict__ o, int n) {
  int i = blockIdx.x * blockDim.x + threadIdx.x;
  if (i < n) o[i] = a[i] + b[i];
}

__global__ void embed_k(const int* __restrict__ x, const int* __restrict__ tgt,
                        const float* __restrict__ emb, unsigned short* __restrict__ xseq) {
  int row = blockIdx.x;          // t*32 + b
  int t = row >> 5, b = row & 31;
  int tok = (t == 0) ? x[b] : tgt[b * 128 + t];
  const float4* e = (const float4*)(emb + (size_t)tok * 1024);
  ushort4* o = (ushort4*)(xseq + (size_t)row * 1024);
  int i = threadIdx.x;
  float4 v = e[i];
  ushort4 u;
  u.x = f2bf(v.x); u.y = f2bf(v.y); u.z = f2bf(v.z); u.w = f2bf(v.w);
  o[i] = u;
}

// ---- bf16 MFMA GEMM: C[M][N] = A[M][K] * B[N][K]^T (+bias[col]) -----------
// (verified in round 1; unchanged)

__global__ __launch_bounds__(256, 2) void gemm_bf16_k(
    const unsigned short* __restrict__ A, const unsigned short* __restrict__ B,
    float* __restrict__ C, const float* __restrict__ bias, int N) {
  __shared__ __align__(16) unsigned short As[128 * 64];
  __shared__ __align__(16) unsigned short Bs[128 * 64];
  const int tid = threadIdx.x;
  const int lane = tid & 63;
  const int w = tid >> 6;
  const int wm = w >> 1, wn = w & 1;
  const int mBase = blockIdx.y * 128;
  const int nBase = blockIdx.x * 128;
  const int lr = lane & 15, lk = lane >> 4;
  const int K = 1024;

  f32x4 acc[4][4];
#pragma unroll
  for (int i = 0; i < 4; ++i)
#pragma unroll
    for (int j = 0; j < 4; ++j) acc[i][j] = (f32x4){0.f, 0.f, 0.f, 0.f};

  for (int kt = 0; kt < K / 64; ++kt) {
    int4 va[4], vb[4];
#pragma unroll
    for (int r = 0; r < 4; ++r) {
      int q = r * 256 + tid;
      int row = q >> 3, c = q & 7;
      va[r] = *(const int4*)(A + (size_t)(mBase + row) * K + kt * 64 + c * 8);
      vb[r] = *(const int4*)(B + (size_t)(nBase + row) * K + kt * 64 + c * 8);
    }
    __syncthreads();
#pragma unroll
    for (int r = 0; r < 4; ++r) {
      int q = r * 256 + tid;
      int row = q >> 3, c = q & 7;
      int cs = c ^ (row & 7);
      *(int4*)&As[row * 64 + cs * 8] = va[r];
      *(int4*)&Bs[row * 64 + cs * 8] = vb[r];
    }
    __syncthreads();
#pragma unroll
    for (int ks = 0; ks < 2; ++ks) {
      short8 a[4], b[4];
#pragma unroll
      for (int mf = 0; mf < 4; ++mf) {
        int row = wm * 64 + mf * 16 + lr;
        int cc = (ks * 4 + lk) ^ (row & 7);
        a[mf] = *(const short8*)&As[row * 64 + cc * 8];
      }
#pragma unroll
      for (int nf = 0; nf < 4; ++nf) {
        int row = wn * 64 + nf * 16 + lr;
        int cc = (ks * 4 + lk) ^ (row & 7);
        b[nf] = *(const short8*)&Bs[row * 64 + cc * 8];
      }
#pragma unroll
      for (int mf = 0; mf < 4; ++mf)
#pragma unroll
        for (int nf = 0; nf < 4; ++nf)
          acc[mf][nf] = MFMA16(a[mf], b[nf], acc[mf][nf]);
    }
  }

#pragma unroll
  for (int mf = 0; mf < 4; ++mf) {
#pragma unroll
    for (int nf = 0; nf < 4; ++nf) {
      int col = nBase + wn * 64 + nf * 16 + lr;
      float bv = bias ? bias[col] : 0.f;
#pragma unroll
      for (int i = 0; i < 4; ++i) {
        int row = mBase + wm * 64 + mf * 16 + lk * 4 + i;
        C[(size_t)row * N + col] = acc[mf][nf][i] + bv;
      }
    }
  }
}

// ---- persistent recurrence kernel -----------------------------------------
// 192 WGs x 256 thr, plain launch, all co-resident (1 WG/CU).
// Blocks 0..63: layer0 (16 units). Blocks 64..191: layer1 (8 units).

struct PParams {
  const float* zx0;             // [128][32][4096]
  const unsigned short* whh0;   // [4096][1024] bf16
  const unsigned short* wih1;   // [4096][1024] bf16
  const unsigned short* whh1;   // [4096][1024] bf16
  const float* bsum1;           // [4096]
  const float* cell;            // [2][32][1024] f32
  unsigned short* h0hist;       // [129][32][1024] bf16
  const unsigned short* h1init; // [32][1024] bf16
  unsigned short* outb;         // [32][128][1024] bf16
  unsigned int* arr0;           // 4 counters, 1KB apart (pre-zeroed)
  unsigned int* arr1;           // 8 counters, 1KB apart (pre-zeroed)
};

__global__ __launch_bounds__(256, 1) void lstm_persist_k(PParams P) {
  const int tid = threadIdx.x;
  const int lane = tid & 63;
  const int w = tid >> 6;
  const int lr = lane & 15, lkk = lane >> 4;

  __shared__ __align__(16) unsigned short wlds[65536];   // 128 KB weight frags
  __shared__ float zbuf[32][68];

  if (blockIdx.x < 64) {
    // ---------------- layer 0: units u0..u0+15 ----------------
    const int u0 = blockIdx.x * 16;
    const int grp = blockIdx.x & 3;
    const int m = w >> 1;
    const int p = w & 1;
    const int g0 = p * 2, g1 = p * 2 + 1;

    for (int f = w; f < 128; f += 4) {
      int g = f >> 5, kc = f & 31;
      const unsigned short* src =
          P.whh0 + (size_t)(g * 1024 + u0 + lr) * 1024 + kc * 32 + lkk * 8;
      *(short8*)&wlds[f * 512 + lane * 8] = *(const short8*)src;
    }
    const int fb = tid >> 3;
    const int jp = tid & 7;
    float creg[2];
    creg[0] = P.cell[fb * 1024 + u0 + 2 * jp];
    creg[1] = P.cell[fb * 1024 + u0 + 2 * jp + 1];
    __syncthreads();

    for (int i = 0; i < 128; ++i) {
      if (i > 0) {
        if (tid < 4) poll_ge(&P.arr0[tid * 256], (unsigned)(16 * i));
        __syncthreads();                      // join polls
        if (tid == 0) __threadfence();        // wbl2+inv: L1/L2 fresh
      }
      __syncthreads();

      float2 zr[4];
      {
        const float2* br = (const float2*)(P.zx0 + (size_t)i * 131072 + fb * 4096 + u0 + 2 * jp);
#pragma unroll
        for (int g = 0; g < 4; ++g) zr[g] = br[g * 512];
      }
      f32x4 acc0 = {0.f, 0.f, 0.f, 0.f}, acc1 = {0.f, 0.f, 0.f, 0.f};
      const unsigned short* ap =
          P.h0hist + (size_t)i * 32768 + (size_t)(m * 16 + lr) * 1024 + lkk * 8;
#pragma unroll
      for (int g4 = 0; g4 < 4; ++g4) {
        short8 a[8];
#pragma unroll
        for (int q = 0; q < 8; ++q) a[q] = *(const short8*)(ap + (g4 * 8 + q) * 32);
#pragma unroll
        for (int q = 0; q < 8; ++q) {
          int kc = g4 * 8 + q;
          short8 b0 = *(const short8*)&wlds[(g0 * 32 + kc) * 512 + lane * 8];
          short8 b1 = *(const short8*)&wlds[(g1 * 32 + kc) * 512 + lane * 8];
          acc0 = MFMA16(a[q], b0, acc0);
          acc1 = MFMA16(a[q], b1, acc1);
        }
      }
#pragma unroll
      for (int j = 0; j < 4; ++j) {
        zbuf[m * 16 + lkk * 4 + j][g0 * 16 + lr] = acc0[j];
        zbuf[m * 16 + lkk * 4 + j][g1 * 16 + lr] = acc1[j];
      }
      __syncthreads();

      unsigned hv = 0;
#pragma unroll
      for (int u = 0; u < 2; ++u) {
        int j = 2 * jp + u;
        float zi = zbuf[fb][j]      + ((u == 0) ? zr[0].x : zr[0].y);
        float zf = zbuf[fb][16 + j] + ((u == 0) ? zr[1].x : zr[1].y);
        float zg = zbuf[fb][32 + j] + ((u == 0) ? zr[2].x : zr[2].y);
        float zo = zbuf[fb][48 + j] + ((u == 0) ? zr[3].x : zr[3].y);
        float ii = 1.f / (1.f + __expf(-zi));
        float ff = 1.f / (1.f + __expf(-zf));
        float gg = tanhf(zg);
        float oo = 1.f / (1.f + __expf(-zo));
        float cn = ff * creg[u] + ii * gg;
        creg[u] = cn;
        float hn = oo * tanhf(cn);
        hv |= ((unsigned)f2bf(hn)) << (16 * u);
      }
      st_u32_dev((unsigned*)&P.h0hist[(size_t)(i + 1) * 32768 + fb * 1024 + u0 + 2 * jp], hv);

      __syncthreads();   // vmcnt(0) drain: sc1 stores at coherence point
      if (tid == 0) arrive(&P.arr0[grp * 256]);
    }
  } else {
    // ---------------- layer 1: units u0..u0+7 ----------------
    const int u0 = (blockIdx.x - 64) * 8;
    const int grp = (blockIdx.x - 64) & 7;
    const int m = w >> 1;
    const int n = w & 1;

    for (int f = w; f < 128; f += 4) {
      int mat = f >> 6, nt = (f >> 5) & 1, kc = f & 31;
      int rr = nt * 16 + lr;
      int gate = rr >> 3, unit = rr & 7;
      const unsigned short* Wm = mat ? P.whh1 : P.wih1;
      const unsigned short* src =
          Wm + (size_t)(gate * 1024 + u0 + unit) * 1024 + kc * 32 + lkk * 8;
      *(short8*)&wlds[f * 512 + lane * 8] = *(const short8*)src;
    }
    const int fb = tid >> 2;
    const int jp = tid & 3;
    float creg[2] = {0.f, 0.f};
    float brg[4][2];
    if (tid < 128) {
      creg[0] = P.cell[32768 + fb * 1024 + u0 + 2 * jp];
      creg[1] = P.cell[32768 + fb * 1024 + u0 + 2 * jp + 1];
#pragma unroll
      for (int g = 0; g < 4; ++g) {
        brg[g][0] = P.bsum1[g * 1024 + u0 + 2 * jp];
        brg[g][1] = P.bsum1[g * 1024 + u0 + 2 * jp + 1];
      }
    }
    __syncthreads();

    for (int i = 1; i <= 128; ++i) {
      if (tid < 12) {
        if (tid < 4) poll_ge(&P.arr0[tid * 256], (unsigned)(16 * i));
        else if (i > 1) poll_ge(&P.arr1[(tid - 4) * 256], (unsigned)(16 * (i - 1)));
      }
      __syncthreads();                      // join polls
      if (tid == 0) __threadfence();        // wbl2+inv: L1/L2 fresh
      __syncthreads();

      f32x4 accA = {0.f, 0.f, 0.f, 0.f}, accB = {0.f, 0.f, 0.f, 0.f};
      const unsigned short* a0p =
          P.h0hist + (size_t)i * 32768 + (size_t)(m * 16 + lr) * 1024 + lkk * 8;
      size_t h1s = (i == 1) ? 1024 : 131072;
      const unsigned short* h1b =
          (i == 1) ? P.h1init : (P.outb + (size_t)(i - 2) * 1024);
      const unsigned short* a1p = h1b + (size_t)(m * 16 + lr) * h1s + lkk * 8;
#pragma unroll
      for (int g4 = 0; g4 < 4; ++g4) {
        short8 a0[8], a1[8];
#pragma unroll
        for (int q = 0; q < 8; ++q) {
          a0[q] = *(const short8*)(a0p + (g4 * 8 + q) * 32);
          a1[q] = *(const short8*)(a1p + (g4 * 8 + q) * 32);
        }
#pragma unroll
        for (int q = 0; q < 8; ++q) {
          int kc = g4 * 8 + q;
          short8 bi = *(const short8*)&wlds[(n * 32 + kc) * 512 + lane * 8];
          short8 bh = *(const short8*)&wlds[(64 + n * 32 + kc) * 512 + lane * 8];
          accA = MFMA16(a0[q], bi, accA);
          accB = MFMA16(a1[q], bh, accB);
        }
      }
      f32x4 acc = accA + accB;
#pragma unroll
      for (int j = 0; j < 4; ++j)
        zbuf[m * 16 + lkk * 4 + j][n * 16 + lr] = acc[j];
      __syncthreads();

      if (tid < 128) {
        unsigned hv = 0;
#pragma unroll
        for (int u = 0; u < 2; ++u) {
          int j = 2 * jp + u;
          float zi = zbuf[fb][j]      + brg[0][u];
          float zf = zbuf[fb][8 + j]  + brg[1][u];
          float zg = zbuf[fb][16 + j] + brg[2][u];
          float zo = zbuf[fb][24 + j] + brg[3][u];
          float ii = 1.f / (1.f + __expf(-zi));
          float ff = 1.f / (1.f + __expf(-zf));
          float gg = tanhf(zg);
          float oo = 1.f / (1.f + __expf(-zo));
          float cn = ff * creg[u] + ii * gg;
          creg[u] = cn;
          float hn = oo * tanhf(cn);
          hv |= ((unsigned)f2bf(hn)) << (16 * u);
        }
        st_u32_dev((unsigned*)&P.outb[(size_t)fb * 131072 + (size_t)(i - 1) * 1024 + u0 + 2 * jp], hv);
      }

      __syncthreads();   // drain outb stores
      if (tid == 0) arrive(&P.arr1[grp * 256]);
    }
  }
}

// ---------------------------------------------------------------------------

extern "C" void kernel_launch(void* const* d_in, const int* in_sizes, int n_in,
                              void* d_out, int out_size, void* d_ws, size_t ws_size,
                              hipStream_t stream) {
  const int*   x      = (const int*)d_in[0];
  const float* hidden = (const float*)d_in[1];
  const float* cell   = (const float*)d_in[2];
  const int*   target = (const int*)d_in[3];
  const float* emb    = (const float*)d_in[5];
  const float* w_ih   = (const float*)d_in[6];
  const float* w_hh   = (const float*)d_in[7];
  const float* b_ih   = (const float*)d_in[8];
  const float* b_hh   = (const float*)d_in[9];
  float* out = (float*)d_out;
  char* ws = (char*)d_ws;

  // ws layout (bytes)
  unsigned short* emb_bf  = (unsigned short*)(ws);                 // 65,536,000
  unsigned short* wih0_bf = (unsigned short*)(ws + 65536000);      //  8,388,608
  unsigned short* whh_bf  = (unsigned short*)(ws + 73924608);      // 16,777,216
  unsigned short* wih1_bf = (unsigned short*)(ws + 90701824);      //  8,388,608
  float*          bsum    = (float*)(ws + 99090432);               //     32,768
  unsigned short* outb    = (unsigned short*)(ws + 99123200);      //  8,388,608
  unsigned int*   barmem  = (unsigned int*)(ws + 107511808);       //     16,384
  // Large transients in d_out's dead space (proj GEMM overwrites last):
  float*          zx0    = (float*)((char*)d_out);                         // 67,108,864
  unsigned short* xseq   = (unsigned short*)((char*)d_out + 67108864);     //  8,388,608
  unsigned short* h0hist = (unsigned short*)((char*)d_out + 75497472);     //  8,454,144
  unsigned short* h1init = (unsigned short*)((char*)d_out + 83951616);     //     65,536

  hipMemsetAsync(barmem, 0, 16384, stream);
  cvt_bf16_k<<<2048, 256, 0, stream>>>(emb, emb_bf, 8192000);
  cvt_bf16_k<<<1024, 256, 0, stream>>>(w_ih, wih0_bf, 1048576);
  cvt_bf16_k<<<2048, 256, 0, stream>>>(w_hh, whh_bf, 2097152);
  cvt_bf16_k<<<1024, 256, 0, stream>>>(w_ih + 4194304, wih1_bf, 1048576);
  cvt_bf16_k<<<32, 256, 0, stream>>>(hidden, h0hist, 8192);          // h0hist[0]
  cvt_bf16_k<<<32, 256, 0, stream>>>(hidden + 32768, h1init, 8192);
  bias_sum_k<<<32, 256, 0, stream>>>(b_ih, b_hh, bsum, 8192);
  embed_k<<<4096, 256, 0, stream>>>(x, target, emb, xseq);

  // Zx0 = x_seq @ w_ih[0]^T + bsum0   [4096 x 4096]
  gemm_bf16_k<<<dim3(32, 32), 256, 0, stream>>>(xseq, wih0_bf, zx0, bsum, 4096);

  // persistent recurrence: 192 WGs, counters + cacheable-read protocol
  PParams pp;
  pp.zx0 = zx0;
  pp.whh0 = whh_bf;
  pp.wih1 = wih1_bf;
  pp.whh1 = whh_bf + 4194304;
  pp.bsum1 = bsum + 4096;
  pp.cell = cell;
  pp.h0hist = h0hist;
  pp.h1init = h1init;
  pp.outb = outb;
  pp.arr0 = barmem;                // 4 counters, 1KB apart
  pp.arr1 = barmem + 4 * 256;      // 8 counters, 1KB apart
  lstm_persist_k<<<192, 256, 0, stream>>>(pp);

  // out = outb @ emb_bf^T   [4096 x 32000]
  gemm_bf16_k<<<dim3(250, 32), 256, 0, stream>>>(outb, emb_bf, out, nullptr, 32000);
}

// Round 9
// 3389.642 us; speedup vs baseline: 5.1028x; 1.0127x over previous
//
#include <hip/hip_runtime.h>
#include <stdint.h>

// ---------------------------------------------------------------------------
// DecoderLSTM: B=32, S=128, H=1024, L=2, V=32000, teacher forcing (tf=1)
//
//   1. cvt weights/emb -> bf16, bsum = b_ih+b_hh, h/c inits.
//   2. embed tokens -> x_seq bf16 [4096][1024] (rows t*32+b)     (in d_out)
//   3. Zx0 = x_seq @ w_ih[0]^T + bsum0  (MFMA GEMM, f32)         (in d_out)
//   4. ONE persistent kernel (round-8 protocol, unchanged): LDS weights,
//      producer/consumer counters, sc1 stores + cacheable reads + per-iter
//      thread0 __threadfence().
//   5. out = outb @ emb_bf^T (MFMA GEMM, M=4096, N=32000, K=1024)
//
//   Round 9: GEMM fixes only. (a) XCD-chunked swizzle, B-panel-major WG
//   order -> each B tile fetched once per XCD L2, reused 32x (FETCH was
//   2.85 GB, 38x ideal). (b) LDS-staged epilogue -> full-cacheline float4
//   row writes (WRITE was 4.6 GB vs 524 MB output: partial-line stores).
// ---------------------------------------------------------------------------

typedef __attribute__((ext_vector_type(8))) short short8;
typedef __attribute__((ext_vector_type(4))) float f32x4;

#define MFMA16(a, b, c) __builtin_amdgcn_mfma_f32_16x16x32_bf16((a), (b), (c), 0, 0, 0)

__device__ __forceinline__ unsigned short f2bf(float f) {
  union { float f; unsigned int u; } v; v.f = f;
  unsigned int u = v.u;
  return (unsigned short)((u + 0x7fffu + ((u >> 16) & 1u)) >> 16);
}

// producer stores: sc1 write-through (device-visible once vmcnt-drained)
__device__ __forceinline__ void st_u32_dev(unsigned* p, unsigned v) {
  __hip_atomic_store(p, v, __ATOMIC_RELAXED, __HIP_MEMORY_SCOPE_AGENT);
}
__device__ __forceinline__ void poll_ge(unsigned* c, unsigned tgt) {
  while (__hip_atomic_load(c, __ATOMIC_RELAXED, __HIP_MEMORY_SCOPE_AGENT) < tgt)
    __builtin_amdgcn_s_sleep(1);
}
__device__ __forceinline__ void arrive(unsigned* c) {
  __hip_atomic_fetch_add(c, 1u, __ATOMIC_RELAXED, __HIP_MEMORY_SCOPE_AGENT);
}

// ---- conversion / small kernels -------------------------------------------

__global__ void cvt_bf16_k(const float* __restrict__ s, unsigned short* __restrict__ d, int n4) {
  int i = blockIdx.x * blockDim.x + threadIdx.x;
  int st = gridDim.x * blockDim.x;
  for (; i < n4; i += st) {
    float4 v = ((const float4*)s)[i];
    ushort4 o;
    o.x = f2bf(v.x); o.y = f2bf(v.y); o.z = f2bf(v.z); o.w = f2bf(v.w);
    ((ushort4*)d)[i] = o;
  }
}

__global__ void bias_sum_k(const float* __restrict__ a, const float* __restrict__ b,
                           float* __restrict__ o, int n) {
  int i = blockIdx.x * blockDim.x + threadIdx.x;
  if (i < n) o[i] = a[i] + b[i];
}

__global__ void embed_k(const int* __restrict__ x, const int* __restrict__ tgt,
                        const float* __restrict__ emb, unsigned short* __restrict__ xseq) {
  int row = blockIdx.x;          // t*32 + b
  int t = row >> 5, b = row & 31;
  int tok = (t == 0) ? x[b] : tgt[b * 128 + t];
  const float4* e = (const float4*)(emb + (size_t)tok * 1024);
  ushort4* o = (ushort4*)(xseq + (size_t)row * 1024);
  int i = threadIdx.x;
  float4 v = e[i];
  ushort4 u;
  u.x = f2bf(v.x); u.y = f2bf(v.y); u.z = f2bf(v.z); u.w = f2bf(v.w);
  o[i] = u;
}

// ---- bf16 MFMA GEMM: C[M][N] = A[M][K] * B[N][K]^T (+bias[col]) -----------
// M fixed = 4096 (32 m-blocks). 1D grid, nwg = 32 * N/128, nwg % 8 == 0.
// XCD-chunked swizzle: lin = (wg&7)*(nwg/8) + (wg>>3); nB = lin>>5, mB=lin&31
// -> each XCD sweeps all mB for a contiguous nB range (B-tile L2 reuse 32x).
// Epilogue: LDS-staged, full-line coalesced float4 row writes.

__global__ __launch_bounds__(256, 2) void gemm_bf16_k(
    const unsigned short* __restrict__ A, const unsigned short* __restrict__ B,
    float* __restrict__ C, const float* __restrict__ bias, int N) {
  __shared__ __align__(16) unsigned short smem[2 * 128 * 64];   // 32 KB
  unsigned short* As = smem;
  unsigned short* Bs = smem + 128 * 64;
  const int tid = threadIdx.x;
  const int lane = tid & 63;
  const int w = tid >> 6;
  const int wm = w >> 1, wn = w & 1;
  const int nQ = gridDim.x >> 3;
  const int lin = (blockIdx.x & 7) * nQ + (blockIdx.x >> 3);
  const int mBase = (lin & 31) * 128;
  const int nBase = (lin >> 5) * 128;
  const int lr = lane & 15, lk = lane >> 4;
  const int K = 1024;

  f32x4 acc[4][4];
#pragma unroll
  for (int i = 0; i < 4; ++i)
#pragma unroll
    for (int j = 0; j < 4; ++j) acc[i][j] = (f32x4){0.f, 0.f, 0.f, 0.f};

  for (int kt = 0; kt < K / 64; ++kt) {
    int4 va[4], vb[4];
#pragma unroll
    for (int r = 0; r < 4; ++r) {
      int q = r * 256 + tid;
      int row = q >> 3, c = q & 7;
      va[r] = *(const int4*)(A + (size_t)(mBase + row) * K + kt * 64 + c * 8);
      vb[r] = *(const int4*)(B + (size_t)(nBase + row) * K + kt * 64 + c * 8);
    }
    __syncthreads();
#pragma unroll
    for (int r = 0; r < 4; ++r) {
      int q = r * 256 + tid;
      int row = q >> 3, c = q & 7;
      int cs = c ^ (row & 7);
      *(int4*)&As[row * 64 + cs * 8] = va[r];
      *(int4*)&Bs[row * 64 + cs * 8] = vb[r];
    }
    __syncthreads();
#pragma unroll
    for (int ks = 0; ks < 2; ++ks) {
      short8 a[4], b[4];
#pragma unroll
      for (int mf = 0; mf < 4; ++mf) {
        int row = wm * 64 + mf * 16 + lr;
        int cc = (ks * 4 + lk) ^ (row & 7);
        a[mf] = *(const short8*)&As[row * 64 + cc * 8];
      }
#pragma unroll
      for (int nf = 0; nf < 4; ++nf) {
        int row = wn * 64 + nf * 16 + lr;
        int cc = (ks * 4 + lk) ^ (row & 7);
        b[nf] = *(const short8*)&Bs[row * 64 + cc * 8];
      }
#pragma unroll
      for (int mf = 0; mf < 4; ++mf)
#pragma unroll
        for (int nf = 0; nf < 4; ++nf)
          acc[mf][nf] = MFMA16(a[mf], b[nf], acc[mf][nf]);
    }
  }

  // epilogue: 4 rounds (one per mf). Stage 32 rows x 128 cols (+bias) in
  // LDS (stride 132 kills bank conflicts), then write full 512B rows.
  float* cst = (float*)smem;      // 32*132*4 = 16.9 KB <= 32 KB
#pragma unroll
  for (int r = 0; r < 4; ++r) {
    __syncthreads();   // previous round's reads / main-loop LDS reads done
#pragma unroll
    for (int nf = 0; nf < 4; ++nf) {
      int col = wn * 64 + nf * 16 + lr;
      float bv = bias ? bias[nBase + col] : 0.f;
#pragma unroll
      for (int i = 0; i < 4; ++i)
        cst[(wm * 16 + lk * 4 + i) * 132 + col] = acc[r][nf][i] + bv;
    }
    __syncthreads();
#pragma unroll
    for (int pss = 0; pss < 4; ++pss) {
      int idx = pss * 256 + tid;
      int rl = idx >> 5, cq = idx & 31;
      int grow = mBase + (rl >> 4) * 64 + r * 16 + (rl & 15);
      float4 v = *(const float4*)&cst[rl * 132 + cq * 4];
      *(float4*)&C[(size_t)grow * N + nBase + cq * 4] = v;
    }
  }
}

// ---- persistent recurrence kernel (IDENTICAL to round 8) ------------------

struct PParams {
  const float* zx0;
  const unsigned short* whh0;
  const unsigned short* wih1;
  const unsigned short* whh1;
  const float* bsum1;
  const float* cell;
  unsigned short* h0hist;
  const unsigned short* h1init;
  unsigned short* outb;
  unsigned int* arr0;
  unsigned int* arr1;
};

__global__ __launch_bounds__(256, 1) void lstm_persist_k(PParams P) {
  const int tid = threadIdx.x;
  const int lane = tid & 63;
  const int w = tid >> 6;
  const int lr = lane & 15, lkk = lane >> 4;

  __shared__ __align__(16) unsigned short wlds[65536];
  __shared__ float zbuf[32][68];

  if (blockIdx.x < 64) {
    const int u0 = blockIdx.x * 16;
    const int grp = blockIdx.x & 3;
    const int m = w >> 1;
    const int p = w & 1;
    const int g0 = p * 2, g1 = p * 2 + 1;

    for (int f = w; f < 128; f += 4) {
      int g = f >> 5, kc = f & 31;
      const unsigned short* src =
          P.whh0 + (size_t)(g * 1024 + u0 + lr) * 1024 + kc * 32 + lkk * 8;
      *(short8*)&wlds[f * 512 + lane * 8] = *(const short8*)src;
    }
    const int fb = tid >> 3;
    const int jp = tid & 7;
    float creg[2];
    creg[0] = P.cell[fb * 1024 + u0 + 2 * jp];
    creg[1] = P.cell[fb * 1024 + u0 + 2 * jp + 1];
    __syncthreads();

    for (int i = 0; i < 128; ++i) {
      if (i > 0) {
        if (tid < 4) poll_ge(&P.arr0[tid * 256], (unsigned)(16 * i));
        __syncthreads();
        if (tid == 0) __threadfence();
      }
      __syncthreads();

      float2 zr[4];
      {
        const float2* br = (const float2*)(P.zx0 + (size_t)i * 131072 + fb * 4096 + u0 + 2 * jp);
#pragma unroll
        for (int g = 0; g < 4; ++g) zr[g] = br[g * 512];
      }
      f32x4 acc0 = {0.f, 0.f, 0.f, 0.f}, acc1 = {0.f, 0.f, 0.f, 0.f};
      const unsigned short* ap =
          P.h0hist + (size_t)i * 32768 + (size_t)(m * 16 + lr) * 1024 + lkk * 8;
#pragma unroll
      for (int g4 = 0; g4 < 4; ++g4) {
        short8 a[8];
#pragma unroll
        for (int q = 0; q < 8; ++q) a[q] = *(const short8*)(ap + (g4 * 8 + q) * 32);
#pragma unroll
        for (int q = 0; q < 8; ++q) {
          int kc = g4 * 8 + q;
          short8 b0 = *(const short8*)&wlds[(g0 * 32 + kc) * 512 + lane * 8];
          short8 b1 = *(const short8*)&wlds[(g1 * 32 + kc) * 512 + lane * 8];
          acc0 = MFMA16(a[q], b0, acc0);
          acc1 = MFMA16(a[q], b1, acc1);
        }
      }
#pragma unroll
      for (int j = 0; j < 4; ++j) {
        zbuf[m * 16 + lkk * 4 + j][g0 * 16 + lr] = acc0[j];
        zbuf[m * 16 + lkk * 4 + j][g1 * 16 + lr] = acc1[j];
      }
      __syncthreads();

      unsigned hv = 0;
#pragma unroll
      for (int u = 0; u < 2; ++u) {
        int j = 2 * jp + u;
        float zi = zbuf[fb][j]      + ((u == 0) ? zr[0].x : zr[0].y);
        float zf = zbuf[fb][16 + j] + ((u == 0) ? zr[1].x : zr[1].y);
        float zg = zbuf[fb][32 + j] + ((u == 0) ? zr[2].x : zr[2].y);
        float zo = zbuf[fb][48 + j] + ((u == 0) ? zr[3].x : zr[3].y);
        float ii = 1.f / (1.f + __expf(-zi));
        float ff = 1.f / (1.f + __expf(-zf));
        float gg = tanhf(zg);
        float oo = 1.f / (1.f + __expf(-zo));
        float cn = ff * creg[u] + ii * gg;
        creg[u] = cn;
        float hn = oo * tanhf(cn);
        hv |= ((unsigned)f2bf(hn)) << (16 * u);
      }
      st_u32_dev((unsigned*)&P.h0hist[(size_t)(i + 1) * 32768 + fb * 1024 + u0 + 2 * jp], hv);

      __syncthreads();
      if (tid == 0) arrive(&P.arr0[grp * 256]);
    }
  } else {
    const int u0 = (blockIdx.x - 64) * 8;
    const int grp = (blockIdx.x - 64) & 7;
    const int m = w >> 1;
    const int n = w & 1;

    for (int f = w; f < 128; f += 4) {
      int mat = f >> 6, nt = (f >> 5) & 1, kc = f & 31;
      int rr = nt * 16 + lr;
      int gate = rr >> 3, unit = rr & 7;
      const unsigned short* Wm = mat ? P.whh1 : P.wih1;
      const unsigned short* src =
          Wm + (size_t)(gate * 1024 + u0 + unit) * 1024 + kc * 32 + lkk * 8;
      *(short8*)&wlds[f * 512 + lane * 8] = *(const short8*)src;
    }
    const int fb = tid >> 2;
    const int jp = tid & 3;
    float creg[2] = {0.f, 0.f};
    float brg[4][2];
    if (tid < 128) {
      creg[0] = P.cell[32768 + fb * 1024 + u0 + 2 * jp];
      creg[1] = P.cell[32768 + fb * 1024 + u0 + 2 * jp + 1];
#pragma unroll
      for (int g = 0; g < 4; ++g) {
        brg[g][0] = P.bsum1[g * 1024 + u0 + 2 * jp];
        brg[g][1] = P.bsum1[g * 1024 + u0 + 2 * jp + 1];
      }
    }
    __syncthreads();

    for (int i = 1; i <= 128; ++i) {
      if (tid < 12) {
        if (tid < 4) poll_ge(&P.arr0[tid * 256], (unsigned)(16 * i));
        else if (i > 1) poll_ge(&P.arr1[(tid - 4) * 256], (unsigned)(16 * (i - 1)));
      }
      __syncthreads();
      if (tid == 0) __threadfence();
      __syncthreads();

      f32x4 accA = {0.f, 0.f, 0.f, 0.f}, accB = {0.f, 0.f, 0.f, 0.f};
      const unsigned short* a0p =
          P.h0hist + (size_t)i * 32768 + (size_t)(m * 16 + lr) * 1024 + lkk * 8;
      size_t h1s = (i == 1) ? 1024 : 131072;
      const unsigned short* h1b =
          (i == 1) ? P.h1init : (P.outb + (size_t)(i - 2) * 1024);
      const unsigned short* a1p = h1b + (size_t)(m * 16 + lr) * h1s + lkk * 8;
#pragma unroll
      for (int g4 = 0; g4 < 4; ++g4) {
        short8 a0[8], a1[8];
#pragma unroll
        for (int q = 0; q < 8; ++q) {
          a0[q] = *(const short8*)(a0p + (g4 * 8 + q) * 32);
          a1[q] = *(const short8*)(a1p + (g4 * 8 + q) * 32);
        }
#pragma unroll
        for (int q = 0; q < 8; ++q) {
          int kc = g4 * 8 + q;
          short8 bi = *(const short8*)&wlds[(n * 32 + kc) * 512 + lane * 8];
          short8 bh = *(const short8*)&wlds[(64 + n * 32 + kc) * 512 + lane * 8];
          accA = MFMA16(a0[q], bi, accA);
          accB = MFMA16(a1[q], bh, accB);
        }
      }
      f32x4 acc = accA + accB;
#pragma unroll
      for (int j = 0; j < 4; ++j)
        zbuf[m * 16 + lkk * 4 + j][n * 16 + lr] = acc[j];
      __syncthreads();

      if (tid < 128) {
        unsigned hv = 0;
#pragma unroll
        for (int u = 0; u < 2; ++u) {
          int j = 2 * jp + u;
          float zi = zbuf[fb][j]      + brg[0][u];
          float zf = zbuf[fb][8 + j]  + brg[1][u];
          float zg = zbuf[fb][16 + j] + brg[2][u];
          float zo = zbuf[fb][24 + j] + brg[3][u];
          float ii = 1.f / (1.f + __expf(-zi));
          float ff = 1.f / (1.f + __expf(-zf));
          float gg = tanhf(zg);
          float oo = 1.f / (1.f + __expf(-zo));
          float cn = ff * creg[u] + ii * gg;
          creg[u] = cn;
          float hn = oo * tanhf(cn);
          hv |= ((unsigned)f2bf(hn)) << (16 * u);
        }
        st_u32_dev((unsigned*)&P.outb[(size_t)fb * 131072 + (size_t)(i - 1) * 1024 + u0 + 2 * jp], hv);
      }

      __syncthreads();
      if (tid == 0) arrive(&P.arr1[grp * 256]);
    }
  }
}

// ---------------------------------------------------------------------------

extern "C" void kernel_launch(void* const* d_in, const int* in_sizes, int n_in,
                              void* d_out, int out_size, void* d_ws, size_t ws_size,
                              hipStream_t stream) {
  const int*   x      = (const int*)d_in[0];
  const float* hidden = (const float*)d_in[1];
  const float* cell   = (const float*)d_in[2];
  const int*   target = (const int*)d_in[3];
  const float* emb    = (const float*)d_in[5];
  const float* w_ih   = (const float*)d_in[6];
  const float* w_hh   = (const float*)d_in[7];
  const float* b_ih   = (const float*)d_in[8];
  const float* b_hh   = (const float*)d_in[9];
  float* out = (float*)d_out;
  char* ws = (char*)d_ws;

  // ws layout (bytes)
  unsigned short* emb_bf  = (unsigned short*)(ws);                 // 65,536,000
  unsigned short* wih0_bf = (unsigned short*)(ws + 65536000);      //  8,388,608
  unsigned short* whh_bf  = (unsigned short*)(ws + 73924608);      // 16,777,216
  unsigned short* wih1_bf = (unsigned short*)(ws + 90701824);      //  8,388,608
  float*          bsum    = (float*)(ws + 99090432);               //     32,768
  unsigned short* outb    = (unsigned short*)(ws + 99123200);      //  8,388,608
  unsigned int*   barmem  = (unsigned int*)(ws + 107511808);       //     16,384
  // Large transients in d_out's dead space (proj GEMM overwrites last):
  float*          zx0    = (float*)((char*)d_out);                         // 67,108,864
  unsigned short* xseq   = (unsigned short*)((char*)d_out + 67108864);     //  8,388,608
  unsigned short* h0hist = (unsigned short*)((char*)d_out + 75497472);     //  8,454,144
  unsigned short* h1init = (unsigned short*)((char*)d_out + 83951616);     //     65,536

  hipMemsetAsync(barmem, 0, 16384, stream);
  cvt_bf16_k<<<2048, 256, 0, stream>>>(emb, emb_bf, 8192000);
  cvt_bf16_k<<<1024, 256, 0, stream>>>(w_ih, wih0_bf, 1048576);
  cvt_bf16_k<<<2048, 256, 0, stream>>>(w_hh, whh_bf, 2097152);
  cvt_bf16_k<<<1024, 256, 0, stream>>>(w_ih + 4194304, wih1_bf, 1048576);
  cvt_bf16_k<<<32, 256, 0, stream>>>(hidden, h0hist, 8192);          // h0hist[0]
  cvt_bf16_k<<<32, 256, 0, stream>>>(hidden + 32768, h1init, 8192);
  bias_sum_k<<<32, 256, 0, stream>>>(b_ih, b_hh, bsum, 8192);
  embed_k<<<4096, 256, 0, stream>>>(x, target, emb, xseq);

  // Zx0 = x_seq @ w_ih[0]^T + bsum0   [4096 x 4096], 1024 WGs (1D swizzled)
  gemm_bf16_k<<<1024, 256, 0, stream>>>(xseq, wih0_bf, zx0, bsum, 4096);

  // persistent recurrence (identical to round 8)
  PParams pp;
  pp.zx0 = zx0;
  pp.whh0 = whh_bf;
  pp.wih1 = wih1_bf;
  pp.whh1 = whh_bf + 4194304;
  pp.bsum1 = bsum + 4096;
  pp.cell = cell;
  pp.h0hist = h0hist;
  pp.h1init = h1init;
  pp.outb = outb;
  pp.arr0 = barmem;                // 4 counters, 1KB apart
  pp.arr1 = barmem + 4 * 256;      // 8 counters, 1KB apart
  lstm_persist_k<<<192, 256, 0, stream>>>(pp);

  // out = outb @ emb_bf^T   [4096 x 32000], 8000 WGs (1D swizzled)
  gemm_bf16_k<<<8000, 256, 0, stream>>>(outb, emb_bf, out, nullptr, 32000);
}

// Round 10
// 3239.095 us; speedup vs baseline: 5.3400x; 1.0465x over previous
//
#include <hip/hip_runtime.h>
#include <stdint.h>

// ---------------------------------------------------------------------------
// DecoderLSTM: B=32, S=128, H=1024, L=2, V=32000, teacher forcing (tf=1)
//
//   1. cvt weights/emb -> bf16, bsum = b_ih+b_hh, h/c inits.
//   2. embed tokens -> x_seq bf16 [4096][1024] (rows t*32+b)     (in d_out)
//   3. Zx0 = x_seq @ w_ih[0]^T + bsum0  (MFMA GEMM, f32)         (in d_out)
//   4. ONE persistent kernel (round-8 protocol, unchanged).
//   5. out = outb @ emb_bf^T (MFMA GEMM, M=4096, N=32000, K=1024)
//
//   Round 10 (GEMM only):
//   (a) A-resident XCD map: xcd=wg&7, nB=(wg>>3)>>2, mB=xcd*4+((wg>>3)&3)
//       -> each XCD's A footprint = 4 tiles = 1 MB, L2-resident all kernel;
//       B streams L3 once/XCD. FETCH was 1.88 GB (A restream), predict <1.1.
//   (b) nontemporal C stores: WRITE was 4.49 GB for 524 MB output (8.6x,
//       pattern-insensitive) -> nt streaming stores test/fix that path.
// ---------------------------------------------------------------------------

typedef __attribute__((ext_vector_type(8))) short short8;
typedef __attribute__((ext_vector_type(4))) float f32x4;

#define MFMA16(a, b, c) __builtin_amdgcn_mfma_f32_16x16x32_bf16((a), (b), (c), 0, 0, 0)

__device__ __forceinline__ unsigned short f2bf(float f) {
  union { float f; unsigned int u; } v; v.f = f;
  unsigned int u = v.u;
  return (unsigned short)((u + 0x7fffu + ((u >> 16) & 1u)) >> 16);
}

// producer stores: sc1 write-through (device-visible once vmcnt-drained)
__device__ __forceinline__ void st_u32_dev(unsigned* p, unsigned v) {
  __hip_atomic_store(p, v, __ATOMIC_RELAXED, __HIP_MEMORY_SCOPE_AGENT);
}
__device__ __forceinline__ void poll_ge(unsigned* c, unsigned tgt) {
  while (__hip_atomic_load(c, __ATOMIC_RELAXED, __HIP_MEMORY_SCOPE_AGENT) < tgt)
    __builtin_amdgcn_s_sleep(1);
}
__device__ __forceinline__ void arrive(unsigned* c) {
  __hip_atomic_fetch_add(c, 1u, __ATOMIC_RELAXED, __HIP_MEMORY_SCOPE_AGENT);
}

// ---- conversion / small kernels -------------------------------------------

__global__ void cvt_bf16_k(const float* __restrict__ s, unsigned short* __restrict__ d, int n4) {
  int i = blockIdx.x * blockDim.x + threadIdx.x;
  int st = gridDim.x * blockDim.x;
  for (; i < n4; i += st) {
    float4 v = ((const float4*)s)[i];
    ushort4 o;
    o.x = f2bf(v.x); o.y = f2bf(v.y); o.z = f2bf(v.z); o.w = f2bf(v.w);
    ((ushort4*)d)[i] = o;
  }
}

__global__ void bias_sum_k(const float* __restrict__ a, const float* __restrict__ b,
                           float* __restrict__ o, int n) {
  int i = blockIdx.x * blockDim.x + threadIdx.x;
  if (i < n) o[i] = a[i] + b[i];
}

__global__ void embed_k(const int* __restrict__ x, const int* __restrict__ tgt,
                        const float* __restrict__ emb, unsigned short* __restrict__ xseq) {
  int row = blockIdx.x;          // t*32 + b
  int t = row >> 5, b = row & 31;
  int tok = (t == 0) ? x[b] : tgt[b * 128 + t];
  const float4* e = (const float4*)(emb + (size_t)tok * 1024);
  ushort4* o = (ushort4*)(xseq + (size_t)row * 1024);
  int i = threadIdx.x;
  float4 v = e[i];
  ushort4 u;
  u.x = f2bf(v.x); u.y = f2bf(v.y); u.z = f2bf(v.z); u.w = f2bf(v.w);
  o[i] = u;
}

// ---- bf16 MFMA GEMM: C[M][N] = A[M][K] * B[N][K]^T (+bias[col]) -----------
// M fixed = 4096 (32 m-blocks). 1D grid, nwg = 32 * N/128, nwg % 32 == 0.
// XCD map: xcd=wg&7, idx=wg>>3; nBase=(idx>>2)*128, mBase=(xcd*4+(idx&3))*128
// -> per-XCD A footprint 1 MB (L2-resident); B streams L3 once per XCD.
// Epilogue: LDS-staged full-line rows, NONTEMPORAL float4 stores.

__global__ __launch_bounds__(256, 2) void gemm_bf16_k(
    const unsigned short* __restrict__ A, const unsigned short* __restrict__ B,
    float* __restrict__ C, const float* __restrict__ bias, int N) {
  __shared__ __align__(16) unsigned short smem[2 * 128 * 64];   // 32 KB
  unsigned short* As = smem;
  unsigned short* Bs = smem + 128 * 64;
  const int tid = threadIdx.x;
  const int lane = tid & 63;
  const int w = tid >> 6;
  const int wm = w >> 1, wn = w & 1;
  const int xcd = blockIdx.x & 7;
  const int idx = blockIdx.x >> 3;
  const int nBase = (idx >> 2) * 128;
  const int mBase = (xcd * 4 + (idx & 3)) * 128;
  const int lr = lane & 15, lk = lane >> 4;
  const int K = 1024;

  f32x4 acc[4][4];
#pragma unroll
  for (int i = 0; i < 4; ++i)
#pragma unroll
    for (int j = 0; j < 4; ++j) acc[i][j] = (f32x4){0.f, 0.f, 0.f, 0.f};

  for (int kt = 0; kt < K / 64; ++kt) {
    int4 va[4], vb[4];
#pragma unroll
    for (int r = 0; r < 4; ++r) {
      int q = r * 256 + tid;
      int row = q >> 3, c = q & 7;
      va[r] = *(const int4*)(A + (size_t)(mBase + row) * K + kt * 64 + c * 8);
      vb[r] = *(const int4*)(B + (size_t)(nBase + row) * K + kt * 64 + c * 8);
    }
    __syncthreads();
#pragma unroll
    for (int r = 0; r < 4; ++r) {
      int q = r * 256 + tid;
      int row = q >> 3, c = q & 7;
      int cs = c ^ (row & 7);
      *(int4*)&As[row * 64 + cs * 8] = va[r];
      *(int4*)&Bs[row * 64 + cs * 8] = vb[r];
    }
    __syncthreads();
#pragma unroll
    for (int ks = 0; ks < 2; ++ks) {
      short8 a[4], b[4];
#pragma unroll
      for (int mf = 0; mf < 4; ++mf) {
        int row = wm * 64 + mf * 16 + lr;
        int cc = (ks * 4 + lk) ^ (row & 7);
        a[mf] = *(const short8*)&As[row * 64 + cc * 8];
      }
#pragma unroll
      for (int nf = 0; nf < 4; ++nf) {
        int row = wn * 64 + nf * 16 + lr;
        int cc = (ks * 4 + lk) ^ (row & 7);
        b[nf] = *(const short8*)&Bs[row * 64 + cc * 8];
      }
#pragma unroll
      for (int mf = 0; mf < 4; ++mf)
#pragma unroll
        for (int nf = 0; nf < 4; ++nf)
          acc[mf][nf] = MFMA16(a[mf], b[nf], acc[mf][nf]);
    }
  }

  // epilogue: 4 rounds (one per mf). Stage 32 rows x 128 cols (+bias) in
  // LDS (stride 132), then write full 512B rows with NT float4 stores.
  float* cst = (float*)smem;      // 32*132*4 = 16.9 KB <= 32 KB
#pragma unroll
  for (int r = 0; r < 4; ++r) {
    __syncthreads();
#pragma unroll
    for (int nf = 0; nf < 4; ++nf) {
      int col = wn * 64 + nf * 16 + lr;
      float bv = bias ? bias[nBase + col] : 0.f;
#pragma unroll
      for (int i = 0; i < 4; ++i)
        cst[(wm * 16 + lk * 4 + i) * 132 + col] = acc[r][nf][i] + bv;
    }
    __syncthreads();
#pragma unroll
    for (int pss = 0; pss < 4; ++pss) {
      int idxq = pss * 256 + tid;
      int rl = idxq >> 5, cq = idxq & 31;
      int grow = mBase + (rl >> 4) * 64 + r * 16 + (rl & 15);
      f32x4 v = *(const f32x4*)&cst[rl * 132 + cq * 4];
      __builtin_nontemporal_store(v, (f32x4*)&C[(size_t)grow * N + nBase + cq * 4]);
    }
  }
}

// ---- persistent recurrence kernel (IDENTICAL to round 8/9) ----------------

struct PParams {
  const float* zx0;
  const unsigned short* whh0;
  const unsigned short* wih1;
  const unsigned short* whh1;
  const float* bsum1;
  const float* cell;
  unsigned short* h0hist;
  const unsigned short* h1init;
  unsigned short* outb;
  unsigned int* arr0;
  unsigned int* arr1;
};

__global__ __launch_bounds__(256, 1) void lstm_persist_k(PParams P) {
  const int tid = threadIdx.x;
  const int lane = tid & 63;
  const int w = tid >> 6;
  const int lr = lane & 15, lkk = lane >> 4;

  __shared__ __align__(16) unsigned short wlds[65536];
  __shared__ float zbuf[32][68];

  if (blockIdx.x < 64) {
    const int u0 = blockIdx.x * 16;
    const int grp = blockIdx.x & 3;
    const int m = w >> 1;
    const int p = w & 1;
    const int g0 = p * 2, g1 = p * 2 + 1;

    for (int f = w; f < 128; f += 4) {
      int g = f >> 5, kc = f & 31;
      const unsigned short* src =
          P.whh0 + (size_t)(g * 1024 + u0 + lr) * 1024 + kc * 32 + lkk * 8;
      *(short8*)&wlds[f * 512 + lane * 8] = *(const short8*)src;
    }
    const int fb = tid >> 3;
    const int jp = tid & 7;
    float creg[2];
    creg[0] = P.cell[fb * 1024 + u0 + 2 * jp];
    creg[1] = P.cell[fb * 1024 + u0 + 2 * jp + 1];
    __syncthreads();

    for (int i = 0; i < 128; ++i) {
      if (i > 0) {
        if (tid < 4) poll_ge(&P.arr0[tid * 256], (unsigned)(16 * i));
        __syncthreads();
        if (tid == 0) __threadfence();
      }
      __syncthreads();

      float2 zr[4];
      {
        const float2* br = (const float2*)(P.zx0 + (size_t)i * 131072 + fb * 4096 + u0 + 2 * jp);
#pragma unroll
        for (int g = 0; g < 4; ++g) zr[g] = br[g * 512];
      }
      f32x4 acc0 = {0.f, 0.f, 0.f, 0.f}, acc1 = {0.f, 0.f, 0.f, 0.f};
      const unsigned short* ap =
          P.h0hist + (size_t)i * 32768 + (size_t)(m * 16 + lr) * 1024 + lkk * 8;
#pragma unroll
      for (int g4 = 0; g4 < 4; ++g4) {
        short8 a[8];
#pragma unroll
        for (int q = 0; q < 8; ++q) a[q] = *(const short8*)(ap + (g4 * 8 + q) * 32);
#pragma unroll
        for (int q = 0; q < 8; ++q) {
          int kc = g4 * 8 + q;
          short8 b0 = *(const short8*)&wlds[(g0 * 32 + kc) * 512 + lane * 8];
          short8 b1 = *(const short8*)&wlds[(g1 * 32 + kc) * 512 + lane * 8];
          acc0 = MFMA16(a[q], b0, acc0);
          acc1 = MFMA16(a[q], b1, acc1);
        }
      }
#pragma unroll
      for (int j = 0; j < 4; ++j) {
        zbuf[m * 16 + lkk * 4 + j][g0 * 16 + lr] = acc0[j];
        zbuf[m * 16 + lkk * 4 + j][g1 * 16 + lr] = acc1[j];
      }
      __syncthreads();

      unsigned hv = 0;
#pragma unroll
      for (int u = 0; u < 2; ++u) {
        int j = 2 * jp + u;
        float zi = zbuf[fb][j]      + ((u == 0) ? zr[0].x : zr[0].y);
        float zf = zbuf[fb][16 + j] + ((u == 0) ? zr[1].x : zr[1].y);
        float zg = zbuf[fb][32 + j] + ((u == 0) ? zr[2].x : zr[2].y);
        float zo = zbuf[fb][48 + j] + ((u == 0) ? zr[3].x : zr[3].y);
        float ii = 1.f / (1.f + __expf(-zi));
        float ff = 1.f / (1.f + __expf(-zf));
        float gg = tanhf(zg);
        float oo = 1.f / (1.f + __expf(-zo));
        float cn = ff * creg[u] + ii * gg;
        creg[u] = cn;
        float hn = oo * tanhf(cn);
        hv |= ((unsigned)f2bf(hn)) << (16 * u);
      }
      st_u32_dev((unsigned*)&P.h0hist[(size_t)(i + 1) * 32768 + fb * 1024 + u0 + 2 * jp], hv);

      __syncthreads();
      if (tid == 0) arrive(&P.arr0[grp * 256]);
    }
  } else {
    const int u0 = (blockIdx.x - 64) * 8;
    const int grp = (blockIdx.x - 64) & 7;
    const int m = w >> 1;
    const int n = w & 1;

    for (int f = w; f < 128; f += 4) {
      int mat = f >> 6, nt = (f >> 5) & 1, kc = f & 31;
      int rr = nt * 16 + lr;
      int gate = rr >> 3, unit = rr & 7;
      const unsigned short* Wm = mat ? P.whh1 : P.wih1;
      const unsigned short* src =
          Wm + (size_t)(gate * 1024 + u0 + unit) * 1024 + kc * 32 + lkk * 8;
      *(short8*)&wlds[f * 512 + lane * 8] = *(const short8*)src;
    }
    const int fb = tid >> 2;
    const int jp = tid & 3;
    float creg[2] = {0.f, 0.f};
    float brg[4][2];
    if (tid < 128) {
      creg[0] = P.cell[32768 + fb * 1024 + u0 + 2 * jp];
      creg[1] = P.cell[32768 + fb * 1024 + u0 + 2 * jp + 1];
#pragma unroll
      for (int g = 0; g < 4; ++g) {
        brg[g][0] = P.bsum1[g * 1024 + u0 + 2 * jp];
        brg[g][1] = P.bsum1[g * 1024 + u0 + 2 * jp + 1];
      }
    }
    __syncthreads();

    for (int i = 1; i <= 128; ++i) {
      if (tid < 12) {
        if (tid < 4) poll_ge(&P.arr0[tid * 256], (unsigned)(16 * i));
        else if (i > 1) poll_ge(&P.arr1[(tid - 4) * 256], (unsigned)(16 * (i - 1)));
      }
      __syncthreads();
      if (tid == 0) __threadfence();
      __syncthreads();

      f32x4 accA = {0.f, 0.f, 0.f, 0.f}, accB = {0.f, 0.f, 0.f, 0.f};
      const unsigned short* a0p =
          P.h0hist + (size_t)i * 32768 + (size_t)(m * 16 + lr) * 1024 + lkk * 8;
      size_t h1s = (i == 1) ? 1024 : 131072;
      const unsigned short* h1b =
          (i == 1) ? P.h1init : (P.outb + (size_t)(i - 2) * 1024);
      const unsigned short* a1p = h1b + (size_t)(m * 16 + lr) * h1s + lkk * 8;
#pragma unroll
      for (int g4 = 0; g4 < 4; ++g4) {
        short8 a0[8], a1[8];
#pragma unroll
        for (int q = 0; q < 8; ++q) {
          a0[q] = *(const short8*)(a0p + (g4 * 8 + q) * 32);
          a1[q] = *(const short8*)(a1p + (g4 * 8 + q) * 32);
        }
#pragma unroll
        for (int q = 0; q < 8; ++q) {
          int kc = g4 * 8 + q;
          short8 bi = *(const short8*)&wlds[(n * 32 + kc) * 512 + lane * 8];
          short8 bh = *(const short8*)&wlds[(64 + n * 32 + kc) * 512 + lane * 8];
          accA = MFMA16(a0[q], bi, accA);
          accB = MFMA16(a1[q], bh, accB);
        }
      }
      f32x4 acc = accA + accB;
#pragma unroll
      for (int j = 0; j < 4; ++j)
        zbuf[m * 16 + lkk * 4 + j][n * 16 + lr] = acc[j];
      __syncthreads();

      if (tid < 128) {
        unsigned hv = 0;
#pragma unroll
        for (int u = 0; u < 2; ++u) {
          int j = 2 * jp + u;
          float zi = zbuf[fb][j]      + brg[0][u];
          float zf = zbuf[fb][8 + j]  + brg[1][u];
          float zg = zbuf[fb][16 + j] + brg[2][u];
          float zo = zbuf[fb][24 + j] + brg[3][u];
          float ii = 1.f / (1.f + __expf(-zi));
          float ff = 1.f / (1.f + __expf(-zf));
          float gg = tanhf(zg);
          float oo = 1.f / (1.f + __expf(-zo));
          float cn = ff * creg[u] + ii * gg;
          creg[u] = cn;
          float hn = oo * tanhf(cn);
          hv |= ((unsigned)f2bf(hn)) << (16 * u);
        }
        st_u32_dev((unsigned*)&P.outb[(size_t)fb * 131072 + (size_t)(i - 1) * 1024 + u0 + 2 * jp], hv);
      }

      __syncthreads();
      if (tid == 0) arrive(&P.arr1[grp * 256]);
    }
  }
}

// ---------------------------------------------------------------------------

extern "C" void kernel_launch(void* const* d_in, const int* in_sizes, int n_in,
                              void* d_out, int out_size, void* d_ws, size_t ws_size,
                              hipStream_t stream) {
  const int*   x      = (const int*)d_in[0];
  const float* hidden = (const float*)d_in[1];
  const float* cell   = (const float*)d_in[2];
  const int*   target = (const int*)d_in[3];
  const float* emb    = (const float*)d_in[5];
  const float* w_ih   = (const float*)d_in[6];
  const float* w_hh   = (const float*)d_in[7];
  const float* b_ih   = (const float*)d_in[8];
  const float* b_hh   = (const float*)d_in[9];
  float* out = (float*)d_out;
  char* ws = (char*)d_ws;

  // ws layout (bytes)
  unsigned short* emb_bf  = (unsigned short*)(ws);                 // 65,536,000
  unsigned short* wih0_bf = (unsigned short*)(ws + 65536000);      //  8,388,608
  unsigned short* whh_bf  = (unsigned short*)(ws + 73924608);      // 16,777,216
  unsigned short* wih1_bf = (unsigned short*)(ws + 90701824);      //  8,388,608
  float*          bsum    = (float*)(ws + 99090432);               //     32,768
  unsigned short* outb    = (unsigned short*)(ws + 99123200);      //  8,388,608
  unsigned int*   barmem  = (unsigned int*)(ws + 107511808);       //     16,384
  // Large transients in d_out's dead space (proj GEMM overwrites last):
  float*          zx0    = (float*)((char*)d_out);                         // 67,108,864
  unsigned short* xseq   = (unsigned short*)((char*)d_out + 67108864);     //  8,388,608
  unsigned short* h0hist = (unsigned short*)((char*)d_out + 75497472);     //  8,454,144
  unsigned short* h1init = (unsigned short*)((char*)d_out + 83951616);     //     65,536

  hipMemsetAsync(barmem, 0, 16384, stream);
  cvt_bf16_k<<<2048, 256, 0, stream>>>(emb, emb_bf, 8192000);
  cvt_bf16_k<<<1024, 256, 0, stream>>>(w_ih, wih0_bf, 1048576);
  cvt_bf16_k<<<2048, 256, 0, stream>>>(w_hh, whh_bf, 2097152);
  cvt_bf16_k<<<1024, 256, 0, stream>>>(w_ih + 4194304, wih1_bf, 1048576);
  cvt_bf16_k<<<32, 256, 0, stream>>>(hidden, h0hist, 8192);          // h0hist[0]
  cvt_bf16_k<<<32, 256, 0, stream>>>(hidden + 32768, h1init, 8192);
  bias_sum_k<<<32, 256, 0, stream>>>(b_ih, b_hh, bsum, 8192);
  embed_k<<<4096, 256, 0, stream>>>(x, target, emb, xseq);

  // Zx0 = x_seq @ w_ih[0]^T + bsum0   [4096 x 4096], 1024 WGs (XCD map)
  gemm_bf16_k<<<1024, 256, 0, stream>>>(xseq, wih0_bf, zx0, bsum, 4096);

  // persistent recurrence (identical to round 8/9)
  PParams pp;
  pp.zx0 = zx0;
  pp.whh0 = whh_bf;
  pp.wih1 = wih1_bf;
  pp.whh1 = whh_bf + 4194304;
  pp.bsum1 = bsum + 4096;
  pp.cell = cell;
  pp.h0hist = h0hist;
  pp.h1init = h1init;
  pp.outb = outb;
  pp.arr0 = barmem;                // 4 counters, 1KB apart
  pp.arr1 = barmem + 4 * 256;      // 8 counters, 1KB apart
  lstm_persist_k<<<192, 256, 0, stream>>>(pp);

  // out = outb @ emb_bf^T   [4096 x 32000], 8000 WGs (XCD map)
  gemm_bf16_k<<<8000, 256, 0, stream>>>(outb, emb_bf, out, nullptr, 32000);
}

// Round 11
// 1992.527 us; speedup vs baseline: 8.6808x; 1.6256x over previous
//
#include <hip/hip_runtime.h>
#include <stdint.h>

// ---------------------------------------------------------------------------
// DecoderLSTM: B=32, S=128, H=1024, L=2, V=32000, teacher forcing (tf=1)
//
//   1. cvt weights/emb -> bf16, bsum = b_ih+b_hh, h/c inits.
//   2. embed tokens -> x_seq bf16 [4096][1024] (rows t*32+b)     (in d_out)
//   3. Zx0 = x_seq @ w_ih[0]^T + bsum0  (MFMA GEMM, f32)         (in d_out)
//   4. ONE persistent kernel (round-8 protocol, unchanged).
//   5. out = outb @ emb_bf^T (MFMA GEMM, M=4096, N=32000, K=1024)
//
//   Round 11 (GEMM only): 2-phase double-buffered K-loop with
//   global_load_lds width=16 (T3-minimal): stage(next) issued BEFORE
//   compute(cur), one vmcnt(0)+barrier per K-step -> load latency hides
//   under MFMA. Swizzle moved to the global SOURCE address (linear LDS
//   dest, unchanged XOR on read) per rule #21. R10 showed the loop was
//   latency-exposed (marginal 11-14 TB/s per GB removed vs 4 TB/s avg).
// ---------------------------------------------------------------------------

typedef __attribute__((ext_vector_type(8))) short short8;
typedef __attribute__((ext_vector_type(4))) float f32x4;

#define MFMA16(a, b, c) __builtin_amdgcn_mfma_f32_16x16x32_bf16((a), (b), (c), 0, 0, 0)

__device__ __forceinline__ unsigned short f2bf(float f) {
  union { float f; unsigned int u; } v; v.f = f;
  unsigned int u = v.u;
  return (unsigned short)((u + 0x7fffu + ((u >> 16) & 1u)) >> 16);
}

__device__ __forceinline__ void gload_lds16(const unsigned short* g, unsigned short* l) {
  __builtin_amdgcn_global_load_lds(
      (const __attribute__((address_space(1))) void*)g,
      (__attribute__((address_space(3))) void*)l, 16, 0, 0);
}

// producer stores: sc1 write-through (device-visible once vmcnt-drained)
__device__ __forceinline__ void st_u32_dev(unsigned* p, unsigned v) {
  __hip_atomic_store(p, v, __ATOMIC_RELAXED, __HIP_MEMORY_SCOPE_AGENT);
}
__device__ __forceinline__ void poll_ge(unsigned* c, unsigned tgt) {
  while (__hip_atomic_load(c, __ATOMIC_RELAXED, __HIP_MEMORY_SCOPE_AGENT) < tgt)
    __builtin_amdgcn_s_sleep(1);
}
__device__ __forceinline__ void arrive(unsigned* c) {
  __hip_atomic_fetch_add(c, 1u, __ATOMIC_RELAXED, __HIP_MEMORY_SCOPE_AGENT);
}

// ---- conversion / small kernels -------------------------------------------

__global__ void cvt_bf16_k(const float* __restrict__ s, unsigned short* __restrict__ d, int n4) {
  int i = blockIdx.x * blockDim.x + threadIdx.x;
  int st = gridDim.x * blockDim.x;
  for (; i < n4; i += st) {
    float4 v = ((const float4*)s)[i];
    ushort4 o;
    o.x = f2bf(v.x); o.y = f2bf(v.y); o.z = f2bf(v.z); o.w = f2bf(v.w);
    ((ushort4*)d)[i] = o;
  }
}

__global__ void bias_sum_k(const float* __restrict__ a, const float* __restrict__ b,
                           float* __restrict__ o, int n) {
  int i = blockIdx.x * blockDim.x + threadIdx.x;
  if (i < n) o[i] = a[i] + b[i];
}

__global__ void embed_k(const int* __restrict__ x, const int* __restrict__ tgt,
                        const float* __restrict__ emb, unsigned short* __restrict__ xseq) {
  int row = blockIdx.x;          // t*32 + b
  int t = row >> 5, b = row & 31;
  int tok = (t == 0) ? x[b] : tgt[b * 128 + t];
  const float4* e = (const float4*)(emb + (size_t)tok * 1024);
  ushort4* o = (ushort4*)(xseq + (size_t)row * 1024);
  int i = threadIdx.x;
  float4 v = e[i];
  ushort4 u;
  u.x = f2bf(v.x); u.y = f2bf(v.y); u.z = f2bf(v.z); u.w = f2bf(v.w);
  o[i] = u;
}

// ---- bf16 MFMA GEMM: C[M][N] = A[M][K] * B[N][K]^T (+bias[col]) -----------
// M fixed = 4096. 1D grid, nwg = 32 * N/128.
// XCD map: xcd=wg&7, idx=wg>>3; nBase=(idx>>2)*128, mBase=(xcd*4+(idx&3))*128
// K-loop: 2-phase dbuf, global_load_lds(16B), pre-swizzled source, one
// barrier per K-step. Epilogue: LDS-staged full-line NT float4 stores.

__global__ __launch_bounds__(256, 2) void gemm_bf16_k(
    const unsigned short* __restrict__ A, const unsigned short* __restrict__ B,
    float* __restrict__ C, const float* __restrict__ bias, int N) {
  // 2 buffers x (A 16KB + B 16KB) = 64 KB
  __shared__ __align__(16) unsigned short smem[32768];
  const int tid = threadIdx.x;
  const int lane = tid & 63;
  const int w = tid >> 6;
  const int wm = w >> 1, wn = w & 1;
  const int xcd = blockIdx.x & 7;
  const int idx = blockIdx.x >> 3;
  const int nBase = (idx >> 2) * 128;
  const int mBase = (xcd * 4 + (idx & 3)) * 128;
  const int lr = lane & 15, lk = lane >> 4;
  const int K = 1024;

  // staging geometry: chunk q = r*256 + tid, row = q>>3, slot c = q&7.
  // linear LDS dest chunk q receives global chunk (row, c ^ (row&7)).
  const int srow = tid >> 3;               // row advance 32 per r
  const int scol = (tid & 7) ^ (srow & 7); // pre-swizzled source chunk
  const int wchunk = tid & 192;            // wave-uniform lds chunk base

  f32x4 acc[4][4];
#pragma unroll
  for (int i = 0; i < 4; ++i)
#pragma unroll
    for (int j = 0; j < 4; ++j) acc[i][j] = (f32x4){0.f, 0.f, 0.f, 0.f};

  const unsigned short* Ag = A + (size_t)mBase * K;
  const unsigned short* Bg = B + (size_t)nBase * K;

  auto stage = [&](int buf, int kt) {
    unsigned short* Ab = smem + buf * 16384;
    unsigned short* Bb = Ab + 8192;
#pragma unroll
    for (int r = 0; r < 4; ++r) {
      int row = r * 32 + srow;
      const unsigned short* ga = Ag + (size_t)row * K + kt * 64 + scol * 8;
      const unsigned short* gb = Bg + (size_t)row * K + kt * 64 + scol * 8;
      gload_lds16(ga, &Ab[(r * 256 + wchunk) * 8]);
      gload_lds16(gb, &Bb[(r * 256 + wchunk) * 8]);
    }
  };

  stage(0, 0);
  __syncthreads();                       // vmcnt(0) drain + barrier
  for (int kt = 0; kt < 16; ++kt) {
    int cur = kt & 1;
    if (kt < 15) stage(cur ^ 1, kt + 1); // issue next tile BEFORE compute
    const unsigned short* Ac = smem + cur * 16384;
    const unsigned short* Bc = Ac + 8192;
#pragma unroll
    for (int ks = 0; ks < 2; ++ks) {
      short8 a[4], b[4];
#pragma unroll
      for (int mf = 0; mf < 4; ++mf) {
        int row = wm * 64 + mf * 16 + lr;
        int cc = (ks * 4 + lk) ^ (row & 7);
        a[mf] = *(const short8*)&Ac[row * 64 + cc * 8];
      }
#pragma unroll
      for (int nf = 0; nf < 4; ++nf) {
        int row = wn * 64 + nf * 16 + lr;
        int cc = (ks * 4 + lk) ^ (row & 7);
        b[nf] = *(const short8*)&Bc[row * 64 + cc * 8];
      }
#pragma unroll
      for (int mf = 0; mf < 4; ++mf)
#pragma unroll
        for (int nf = 0; nf < 4; ++nf)
          acc[mf][nf] = MFMA16(a[mf], b[nf], acc[mf][nf]);
    }
    __syncthreads();                     // drains this iter's stage loads
  }

  // epilogue: 4 rounds (one per mf). Stage 32 rows x 128 cols (+bias) in
  // LDS (stride 132), then write full 512B rows with NT float4 stores.
  float* cst = (float*)smem;      // 16.9 KB, reuses staging LDS
#pragma unroll
  for (int r = 0; r < 4; ++r) {
    __syncthreads();
#pragma unroll
    for (int nf = 0; nf < 4; ++nf) {
      int col = wn * 64 + nf * 16 + lr;
      float bv = bias ? bias[nBase + col] : 0.f;
#pragma unroll
      for (int i = 0; i < 4; ++i)
        cst[(wm * 16 + lk * 4 + i) * 132 + col] = acc[r][nf][i] + bv;
    }
    __syncthreads();
#pragma unroll
    for (int pss = 0; pss < 4; ++pss) {
      int idxq = pss * 256 + tid;
      int rl = idxq >> 5, cq = idxq & 31;
      int grow = mBase + (rl >> 4) * 64 + r * 16 + (rl & 15);
      f32x4 v = *(const f32x4*)&cst[rl * 132 + cq * 4];
      __builtin_nontemporal_store(v, (f32x4*)&C[(size_t)grow * N + nBase + cq * 4]);
    }
  }
}

// ---- persistent recurrence kernel (IDENTICAL to round 8/9/10) -------------

struct PParams {
  const float* zx0;
  const unsigned short* whh0;
  const unsigned short* wih1;
  const unsigned short* whh1;
  const float* bsum1;
  const float* cell;
  unsigned short* h0hist;
  const unsigned short* h1init;
  unsigned short* outb;
  unsigned int* arr0;
  unsigned int* arr1;
};

__global__ __launch_bounds__(256, 1) void lstm_persist_k(PParams P) {
  const int tid = threadIdx.x;
  const int lane = tid & 63;
  const int w = tid >> 6;
  const int lr = lane & 15, lkk = lane >> 4;

  __shared__ __align__(16) unsigned short wlds[65536];
  __shared__ float zbuf[32][68];

  if (blockIdx.x < 64) {
    const int u0 = blockIdx.x * 16;
    const int grp = blockIdx.x & 3;
    const int m = w >> 1;
    const int p = w & 1;
    const int g0 = p * 2, g1 = p * 2 + 1;

    for (int f = w; f < 128; f += 4) {
      int g = f >> 5, kc = f & 31;
      const unsigned short* src =
          P.whh0 + (size_t)(g * 1024 + u0 + lr) * 1024 + kc * 32 + lkk * 8;
      *(short8*)&wlds[f * 512 + lane * 8] = *(const short8*)src;
    }
    const int fb = tid >> 3;
    const int jp = tid & 7;
    float creg[2];
    creg[0] = P.cell[fb * 1024 + u0 + 2 * jp];
    creg[1] = P.cell[fb * 1024 + u0 + 2 * jp + 1];
    __syncthreads();

    for (int i = 0; i < 128; ++i) {
      if (i > 0) {
        if (tid < 4) poll_ge(&P.arr0[tid * 256], (unsigned)(16 * i));
        __syncthreads();
        if (tid == 0) __threadfence();
      }
      __syncthreads();

      float2 zr[4];
      {
        const float2* br = (const float2*)(P.zx0 + (size_t)i * 131072 + fb * 4096 + u0 + 2 * jp);
#pragma unroll
        for (int g = 0; g < 4; ++g) zr[g] = br[g * 512];
      }
      f32x4 acc0 = {0.f, 0.f, 0.f, 0.f}, acc1 = {0.f, 0.f, 0.f, 0.f};
      const unsigned short* ap =
          P.h0hist + (size_t)i * 32768 + (size_t)(m * 16 + lr) * 1024 + lkk * 8;
#pragma unroll
      for (int g4 = 0; g4 < 4; ++g4) {
        short8 a[8];
#pragma unroll
        for (int q = 0; q < 8; ++q) a[q] = *(const short8*)(ap + (g4 * 8 + q) * 32);
#pragma unroll
        for (int q = 0; q < 8; ++q) {
          int kc = g4 * 8 + q;
          short8 b0 = *(const short8*)&wlds[(g0 * 32 + kc) * 512 + lane * 8];
          short8 b1 = *(const short8*)&wlds[(g1 * 32 + kc) * 512 + lane * 8];
          acc0 = MFMA16(a[q], b0, acc0);
          acc1 = MFMA16(a[q], b1, acc1);
        }
      }
#pragma unroll
      for (int j = 0; j < 4; ++j) {
        zbuf[m * 16 + lkk * 4 + j][g0 * 16 + lr] = acc0[j];
        zbuf[m * 16 + lkk * 4 + j][g1 * 16 + lr] = acc1[j];
      }
      __syncthreads();

      unsigned hv = 0;
#pragma unroll
      for (int u = 0; u < 2; ++u) {
        int j = 2 * jp + u;
        float zi = zbuf[fb][j]      + ((u == 0) ? zr[0].x : zr[0].y);
        float zf = zbuf[fb][16 + j] + ((u == 0) ? zr[1].x : zr[1].y);
        float zg = zbuf[fb][32 + j] + ((u == 0) ? zr[2].x : zr[2].y);
        float zo = zbuf[fb][48 + j] + ((u == 0) ? zr[3].x : zr[3].y);
        float ii = 1.f / (1.f + __expf(-zi));
        float ff = 1.f / (1.f + __expf(-zf));
        float gg = tanhf(zg);
        float oo = 1.f / (1.f + __expf(-zo));
        float cn = ff * creg[u] + ii * gg;
        creg[u] = cn;
        float hn = oo * tanhf(cn);
        hv |= ((unsigned)f2bf(hn)) << (16 * u);
      }
      st_u32_dev((unsigned*)&P.h0hist[(size_t)(i + 1) * 32768 + fb * 1024 + u0 + 2 * jp], hv);

      __syncthreads();
      if (tid == 0) arrive(&P.arr0[grp * 256]);
    }
  } else {
    const int u0 = (blockIdx.x - 64) * 8;
    const int grp = (blockIdx.x - 64) & 7;
    const int m = w >> 1;
    const int n = w & 1;

    for (int f = w; f < 128; f += 4) {
      int mat = f >> 6, nt = (f >> 5) & 1, kc = f & 31;
      int rr = nt * 16 + lr;
      int gate = rr >> 3, unit = rr & 7;
      const unsigned short* Wm = mat ? P.whh1 : P.wih1;
      const unsigned short* src =
          Wm + (size_t)(gate * 1024 + u0 + unit) * 1024 + kc * 32 + lkk * 8;
      *(short8*)&wlds[f * 512 + lane * 8] = *(const short8*)src;
    }
    const int fb = tid >> 2;
    const int jp = tid & 3;
    float creg[2] = {0.f, 0.f};
    float brg[4][2];
    if (tid < 128) {
      creg[0] = P.cell[32768 + fb * 1024 + u0 + 2 * jp];
      creg[1] = P.cell[32768 + fb * 1024 + u0 + 2 * jp + 1];
#pragma unroll
      for (int g = 0; g < 4; ++g) {
        brg[g][0] = P.bsum1[g * 1024 + u0 + 2 * jp];
        brg[g][1] = P.bsum1[g * 1024 + u0 + 2 * jp + 1];
      }
    }
    __syncthreads();

    for (int i = 1; i <= 128; ++i) {
      if (tid < 12) {
        if (tid < 4) poll_ge(&P.arr0[tid * 256], (unsigned)(16 * i));
        else if (i > 1) poll_ge(&P.arr1[(tid - 4) * 256], (unsigned)(16 * (i - 1)));
      }
      __syncthreads();
      if (tid == 0) __threadfence();
      __syncthreads();

      f32x4 accA = {0.f, 0.f, 0.f, 0.f}, accB = {0.f, 0.f, 0.f, 0.f};
      const unsigned short* a0p =
          P.h0hist + (size_t)i * 32768 + (size_t)(m * 16 + lr) * 1024 + lkk * 8;
      size_t h1s = (i == 1) ? 1024 : 131072;
      const unsigned short* h1b =
          (i == 1) ? P.h1init : (P.outb + (size_t)(i - 2) * 1024);
      const unsigned short* a1p = h1b + (size_t)(m * 16 + lr) * h1s + lkk * 8;
#pragma unroll
      for (int g4 = 0; g4 < 4; ++g4) {
        short8 a0[8], a1[8];
#pragma unroll
        for (int q = 0; q < 8; ++q) {
          a0[q] = *(const short8*)(a0p + (g4 * 8 + q) * 32);
          a1[q] = *(const short8*)(a1p + (g4 * 8 + q) * 32);
        }
#pragma unroll
        for (int q = 0; q < 8; ++q) {
          int kc = g4 * 8 + q;
          short8 bi = *(const short8*)&wlds[(n * 32 + kc) * 512 + lane * 8];
          short8 bh = *(const short8*)&wlds[(64 + n * 32 + kc) * 512 + lane * 8];
          accA = MFMA16(a0[q], bi, accA);
          accB = MFMA16(a1[q], bh, accB);
        }
      }
      f32x4 acc = accA + accB;
#pragma unroll
      for (int j = 0; j < 4; ++j)
        zbuf[m * 16 + lkk * 4 + j][n * 16 + lr] = acc[j];
      __syncthreads();

      if (tid < 128) {
        unsigned hv = 0;
#pragma unroll
        for (int u = 0; u < 2; ++u) {
          int j = 2 * jp + u;
          float zi = zbuf[fb][j]      + brg[0][u];
          float zf = zbuf[fb][8 + j]  + brg[1][u];
          float zg = zbuf[fb][16 + j] + brg[2][u];
          float zo = zbuf[fb][24 + j] + brg[3][u];
          float ii = 1.f / (1.f + __expf(-zi));
          float ff = 1.f / (1.f + __expf(-zf));
          float gg = tanhf(zg);
          float oo = 1.f / (1.f + __expf(-zo));
          float cn = ff * creg[u] + ii * gg;
          creg[u] = cn;
          float hn = oo * tanhf(cn);
          hv |= ((unsigned)f2bf(hn)) << (16 * u);
        }
        st_u32_dev((unsigned*)&P.outb[(size_t)fb * 131072 + (size_t)(i - 1) * 1024 + u0 + 2 * jp], hv);
      }

      __syncthreads();
      if (tid == 0) arrive(&P.arr1[grp * 256]);
    }
  }
}

// ---------------------------------------------------------------------------

extern "C" void kernel_launch(void* const* d_in, const int* in_sizes, int n_in,
                              void* d_out, int out_size, void* d_ws, size_t ws_size,
                              hipStream_t stream) {
  const int*   x      = (const int*)d_in[0];
  const float* hidden = (const float*)d_in[1];
  const float* cell   = (const float*)d_in[2];
  const int*   target = (const int*)d_in[3];
  const float* emb    = (const float*)d_in[5];
  const float* w_ih   = (const float*)d_in[6];
  const float* w_hh   = (const float*)d_in[7];
  const float* b_ih   = (const float*)d_in[8];
  const float* b_hh   = (const float*)d_in[9];
  float* out = (float*)d_out;
  char* ws = (char*)d_ws;

  // ws layout (bytes)
  unsigned short* emb_bf  = (unsigned short*)(ws);                 // 65,536,000
  unsigned short* wih0_bf = (unsigned short*)(ws + 65536000);      //  8,388,608
  unsigned short* whh_bf  = (unsigned short*)(ws + 73924608);      // 16,777,216
  unsigned short* wih1_bf = (unsigned short*)(ws + 90701824);      //  8,388,608
  float*          bsum    = (float*)(ws + 99090432);               //     32,768
  unsigned short* outb    = (unsigned short*)(ws + 99123200);      //  8,388,608
  unsigned int*   barmem  = (unsigned int*)(ws + 107511808);       //     16,384
  // Large transients in d_out's dead space (proj GEMM overwrites last):
  float*          zx0    = (float*)((char*)d_out);                         // 67,108,864
  unsigned short* xseq   = (unsigned short*)((char*)d_out + 67108864);     //  8,388,608
  unsigned short* h0hist = (unsigned short*)((char*)d_out + 75497472);     //  8,454,144
  unsigned short* h1init = (unsigned short*)((char*)d_out + 83951616);     //     65,536

  hipMemsetAsync(barmem, 0, 16384, stream);
  cvt_bf16_k<<<2048, 256, 0, stream>>>(emb, emb_bf, 8192000);
  cvt_bf16_k<<<1024, 256, 0, stream>>>(w_ih, wih0_bf, 1048576);
  cvt_bf16_k<<<2048, 256, 0, stream>>>(w_hh, whh_bf, 2097152);
  cvt_bf16_k<<<1024, 256, 0, stream>>>(w_ih + 4194304, wih1_bf, 1048576);
  cvt_bf16_k<<<32, 256, 0, stream>>>(hidden, h0hist, 8192);          // h0hist[0]
  cvt_bf16_k<<<32, 256, 0, stream>>>(hidden + 32768, h1init, 8192);
  bias_sum_k<<<32, 256, 0, stream>>>(b_ih, b_hh, bsum, 8192);
  embed_k<<<4096, 256, 0, stream>>>(x, target, emb, xseq);

  // Zx0 = x_seq @ w_ih[0]^T + bsum0   [4096 x 4096], 1024 WGs (XCD map)
  gemm_bf16_k<<<1024, 256, 0, stream>>>(xseq, wih0_bf, zx0, bsum, 4096);

  // persistent recurrence (identical to rounds 8-10)
  PParams pp;
  pp.zx0 = zx0;
  pp.whh0 = whh_bf;
  pp.wih1 = wih1_bf;
  pp.whh1 = whh_bf + 4194304;
  pp.bsum1 = bsum + 4096;
  pp.cell = cell;
  pp.h0hist = h0hist;
  pp.h1init = h1init;
  pp.outb = outb;
  pp.arr0 = barmem;                // 4 counters, 1KB apart
  pp.arr1 = barmem + 4 * 256;      // 8 counters, 1KB apart
  lstm_persist_k<<<192, 256, 0, stream>>>(pp);

  // out = outb @ emb_bf^T   [4096 x 32000], 8000 WGs (XCD map)
  gemm_bf16_k<<<8000, 256, 0, stream>>>(outb, emb_bf, out, nullptr, 32000);
}

// Round 12
// 1578.849 us; speedup vs baseline: 10.9553x; 1.2620x over previous
//
#include <hip/hip_runtime.h>
#include <stdint.h>

// ---------------------------------------------------------------------------
// DecoderLSTM: B=32, S=128, H=1024, L=2, V=32000, teacher forcing (tf=1)
//
//   1. cvt weights/emb -> bf16, bsum = b_ih+b_hh, h/c inits.
//   2. embed tokens -> x_seq bf16 [4096][1024] (rows t*32+b)     (in d_out)
//   3. Zx0 = x_seq @ w_ih[0]^T + bsum0  (MFMA GEMM, f32)         (in d_out)
//   4. ONE persistent kernel. Weights in LDS. Producer/consumer counters.
//      h via sc1 write-through stores + PLAIN CACHEABLE loads, NO per-iter
//      fence (round 12): all cross-WG data is in rolling history buffers --
//      each line written once (visible at L3 before the counter arrive) and
//      read at addresses the consumer XCD's L1/L2 never cached during this
//      kernel -> no stale copies possible. R11's per-WG __threadfence
//      (whole-L2 inv, 24x per XCD per iter) was defeating L2 sharing.
//   5. out = outb @ emb_bf^T (MFMA GEMM, M=4096, N=32000, K=1024)
// ---------------------------------------------------------------------------

typedef __attribute__((ext_vector_type(8))) short short8;
typedef __attribute__((ext_vector_type(4))) float f32x4;

#define MFMA16(a, b, c) __builtin_amdgcn_mfma_f32_16x16x32_bf16((a), (b), (c), 0, 0, 0)

__device__ __forceinline__ unsigned short f2bf(float f) {
  union { float f; unsigned int u; } v; v.f = f;
  unsigned int u = v.u;
  return (unsigned short)((u + 0x7fffu + ((u >> 16) & 1u)) >> 16);
}

__device__ __forceinline__ void gload_lds16(const unsigned short* g, unsigned short* l) {
  __builtin_amdgcn_global_load_lds(
      (const __attribute__((address_space(1))) void*)g,
      (__attribute__((address_space(3))) void*)l, 16, 0, 0);
}

// producer stores: sc1 write-through (device-visible once vmcnt-drained)
__device__ __forceinline__ void st_u32_dev(unsigned* p, unsigned v) {
  __hip_atomic_store(p, v, __ATOMIC_RELAXED, __HIP_MEMORY_SCOPE_AGENT);
}
__device__ __forceinline__ void poll_ge(unsigned* c, unsigned tgt) {
  while (__hip_atomic_load(c, __ATOMIC_RELAXED, __HIP_MEMORY_SCOPE_AGENT) < tgt)
    __builtin_amdgcn_s_sleep(1);
}
__device__ __forceinline__ void arrive(unsigned* c) {
  __hip_atomic_fetch_add(c, 1u, __ATOMIC_RELAXED, __HIP_MEMORY_SCOPE_AGENT);
}

// ---- conversion / small kernels -------------------------------------------

__global__ void cvt_bf16_k(const float* __restrict__ s, unsigned short* __restrict__ d, int n4) {
  int i = blockIdx.x * blockDim.x + threadIdx.x;
  int st = gridDim.x * blockDim.x;
  for (; i < n4; i += st) {
    float4 v = ((const float4*)s)[i];
    ushort4 o;
    o.x = f2bf(v.x); o.y = f2bf(v.y); o.z = f2bf(v.z); o.w = f2bf(v.w);
    ((ushort4*)d)[i] = o;
  }
}

__global__ void bias_sum_k(const float* __restrict__ a, const float* __restrict__ b,
                           float* __restrict__ o, int n) {
  int i = blockIdx.x * blockDim.x + threadIdx.x;
  if (i < n) o[i] = a[i] + b[i];
}

__global__ void embed_k(const int* __restrict__ x, const int* __restrict__ tgt,
                        const float* __restrict__ emb, unsigned short* __restrict__ xseq) {
  int row = blockIdx.x;          // t*32 + b
  int t = row >> 5, b = row & 31;
  int tok = (t == 0) ? x[b] : tgt[b * 128 + t];
  const float4* e = (const float4*)(emb + (size_t)tok * 1024);
  ushort4* o = (ushort4*)(xseq + (size_t)row * 1024);
  int i = threadIdx.x;
  float4 v = e[i];
  ushort4 u;
  u.x = f2bf(v.x); u.y = f2bf(v.y); u.z = f2bf(v.z); u.w = f2bf(v.w);
  o[i] = u;
}

// ---- bf16 MFMA GEMM: C[M][N] = A[M][K] * B[N][K]^T (+bias[col]) -----------
// (round-11 2-phase pipelined version, verified: proj 1552 -> ~300 us)

__global__ __launch_bounds__(256, 2) void gemm_bf16_k(
    const unsigned short* __restrict__ A, const unsigned short* __restrict__ B,
    float* __restrict__ C, const float* __restrict__ bias, int N) {
  __shared__ __align__(16) unsigned short smem[32768];   // 2 x (A16K + B16K)
  const int tid = threadIdx.x;
  const int lane = tid & 63;
  const int w = tid >> 6;
  const int wm = w >> 1, wn = w & 1;
  const int xcd = blockIdx.x & 7;
  const int idx = blockIdx.x >> 3;
  const int nBase = (idx >> 2) * 128;
  const int mBase = (xcd * 4 + (idx & 3)) * 128;
  const int lr = lane & 15, lk = lane >> 4;
  const int K = 1024;

  const int srow = tid >> 3;
  const int scol = (tid & 7) ^ (srow & 7);
  const int wchunk = tid & 192;

  f32x4 acc[4][4];
#pragma unroll
  for (int i = 0; i < 4; ++i)
#pragma unroll
    for (int j = 0; j < 4; ++j) acc[i][j] = (f32x4){0.f, 0.f, 0.f, 0.f};

  const unsigned short* Ag = A + (size_t)mBase * K;
  const unsigned short* Bg = B + (size_t)nBase * K;

  auto stage = [&](int buf, int kt) {
    unsigned short* Ab = smem + buf * 16384;
    unsigned short* Bb = Ab + 8192;
#pragma unroll
    for (int r = 0; r < 4; ++r) {
      int row = r * 32 + srow;
      const unsigned short* ga = Ag + (size_t)row * K + kt * 64 + scol * 8;
      const unsigned short* gb = Bg + (size_t)row * K + kt * 64 + scol * 8;
      gload_lds16(ga, &Ab[(r * 256 + wchunk) * 8]);
      gload_lds16(gb, &Bb[(r * 256 + wchunk) * 8]);
    }
  };

  stage(0, 0);
  __syncthreads();
  for (int kt = 0; kt < 16; ++kt) {
    int cur = kt & 1;
    if (kt < 15) stage(cur ^ 1, kt + 1);
    const unsigned short* Ac = smem + cur * 16384;
    const unsigned short* Bc = Ac + 8192;
#pragma unroll
    for (int ks = 0; ks < 2; ++ks) {
      short8 a[4], b[4];
#pragma unroll
      for (int mf = 0; mf < 4; ++mf) {
        int row = wm * 64 + mf * 16 + lr;
        int cc = (ks * 4 + lk) ^ (row & 7);
        a[mf] = *(const short8*)&Ac[row * 64 + cc * 8];
      }
#pragma unroll
      for (int nf = 0; nf < 4; ++nf) {
        int row = wn * 64 + nf * 16 + lr;
        int cc = (ks * 4 + lk) ^ (row & 7);
        b[nf] = *(const short8*)&Bc[row * 64 + cc * 8];
      }
#pragma unroll
      for (int mf = 0; mf < 4; ++mf)
#pragma unroll
        for (int nf = 0; nf < 4; ++nf)
          acc[mf][nf] = MFMA16(a[mf], b[nf], acc[mf][nf]);
    }
    __syncthreads();
  }

  float* cst = (float*)smem;
#pragma unroll
  for (int r = 0; r < 4; ++r) {
    __syncthreads();
#pragma unroll
    for (int nf = 0; nf < 4; ++nf) {
      int col = wn * 64 + nf * 16 + lr;
      float bv = bias ? bias[nBase + col] : 0.f;
#pragma unroll
      for (int i = 0; i < 4; ++i)
        cst[(wm * 16 + lk * 4 + i) * 132 + col] = acc[r][nf][i] + bv;
    }
    __syncthreads();
#pragma unroll
    for (int pss = 0; pss < 4; ++pss) {
      int idxq = pss * 256 + tid;
      int rl = idxq >> 5, cq = idxq & 31;
      int grow = mBase + (rl >> 4) * 64 + r * 16 + (rl & 15);
      f32x4 v = *(const f32x4*)&cst[rl * 132 + cq * 4];
      __builtin_nontemporal_store(v, (f32x4*)&C[(size_t)grow * N + nBase + cq * 4]);
    }
  }
}

// ---- persistent recurrence kernel -----------------------------------------
// Round 12: NO per-iteration fence. Rolling-history addresses make plain
// cacheable loads coherent (virgin lines in consumer L1/L2).

struct PParams {
  const float* zx0;
  const unsigned short* whh0;
  const unsigned short* wih1;
  const unsigned short* whh1;
  const float* bsum1;
  const float* cell;
  unsigned short* h0hist;
  const unsigned short* h1init;
  unsigned short* outb;
  unsigned int* arr0;
  unsigned int* arr1;
};

__global__ __launch_bounds__(256, 1) void lstm_persist_k(PParams P) {
  const int tid = threadIdx.x;
  const int lane = tid & 63;
  const int w = tid >> 6;
  const int lr = lane & 15, lkk = lane >> 4;

  __shared__ __align__(16) unsigned short wlds[65536];
  __shared__ float zbuf[32][68];

  if (blockIdx.x < 64) {
    const int u0 = blockIdx.x * 16;
    const int grp = blockIdx.x & 3;
    const int m = w >> 1;
    const int p = w & 1;
    const int g0 = p * 2, g1 = p * 2 + 1;

    for (int f = w; f < 128; f += 4) {
      int g = f >> 5, kc = f & 31;
      const unsigned short* src =
          P.whh0 + (size_t)(g * 1024 + u0 + lr) * 1024 + kc * 32 + lkk * 8;
      *(short8*)&wlds[f * 512 + lane * 8] = *(const short8*)src;
    }
    const int fb = tid >> 3;
    const int jp = tid & 7;
    float creg[2];
    creg[0] = P.cell[fb * 1024 + u0 + 2 * jp];
    creg[1] = P.cell[fb * 1024 + u0 + 2 * jp + 1];
    __syncthreads();

    for (int i = 0; i < 128; ++i) {
      if (i > 0) {
        if (tid < 4) poll_ge(&P.arr0[tid * 256], (unsigned)(16 * i));
      }
      __syncthreads();   // all lanes held until polls complete

      float2 zr[4];
      {
        const float2* br = (const float2*)(P.zx0 + (size_t)i * 131072 + fb * 4096 + u0 + 2 * jp);
#pragma unroll
        for (int g = 0; g < 4; ++g) zr[g] = br[g * 512];
      }
      f32x4 acc0 = {0.f, 0.f, 0.f, 0.f}, acc1 = {0.f, 0.f, 0.f, 0.f};
      const unsigned short* ap =
          P.h0hist + (size_t)i * 32768 + (size_t)(m * 16 + lr) * 1024 + lkk * 8;
#pragma unroll
      for (int g4 = 0; g4 < 4; ++g4) {
        short8 a[8];
#pragma unroll
        for (int q = 0; q < 8; ++q) a[q] = *(const short8*)(ap + (g4 * 8 + q) * 32);
#pragma unroll
        for (int q = 0; q < 8; ++q) {
          int kc = g4 * 8 + q;
          short8 b0 = *(const short8*)&wlds[(g0 * 32 + kc) * 512 + lane * 8];
          short8 b1 = *(const short8*)&wlds[(g1 * 32 + kc) * 512 + lane * 8];
          acc0 = MFMA16(a[q], b0, acc0);
          acc1 = MFMA16(a[q], b1, acc1);
        }
      }
#pragma unroll
      for (int j = 0; j < 4; ++j) {
        zbuf[m * 16 + lkk * 4 + j][g0 * 16 + lr] = acc0[j];
        zbuf[m * 16 + lkk * 4 + j][g1 * 16 + lr] = acc1[j];
      }
      __syncthreads();

      unsigned hv = 0;
#pragma unroll
      for (int u = 0; u < 2; ++u) {
        int j = 2 * jp + u;
        float zi = zbuf[fb][j]      + ((u == 0) ? zr[0].x : zr[0].y);
        float zf = zbuf[fb][16 + j] + ((u == 0) ? zr[1].x : zr[1].y);
        float zg = zbuf[fb][32 + j] + ((u == 0) ? zr[2].x : zr[2].y);
        float zo = zbuf[fb][48 + j] + ((u == 0) ? zr[3].x : zr[3].y);
        float ii = 1.f / (1.f + __expf(-zi));
        float ff = 1.f / (1.f + __expf(-zf));
        float gg = tanhf(zg);
        float oo = 1.f / (1.f + __expf(-zo));
        float cn = ff * creg[u] + ii * gg;
        creg[u] = cn;
        float hn = oo * tanhf(cn);
        hv |= ((unsigned)f2bf(hn)) << (16 * u);
      }
      st_u32_dev((unsigned*)&P.h0hist[(size_t)(i + 1) * 32768 + fb * 1024 + u0 + 2 * jp], hv);

      __syncthreads();   // vmcnt(0) drain: sc1 stores at coherence point
      if (tid == 0) arrive(&P.arr0[grp * 256]);
    }
  } else {
    const int u0 = (blockIdx.x - 64) * 8;
    const int grp = (blockIdx.x - 64) & 7;
    const int m = w >> 1;
    const int n = w & 1;

    for (int f = w; f < 128; f += 4) {
      int mat = f >> 6, nt = (f >> 5) & 1, kc = f & 31;
      int rr = nt * 16 + lr;
      int gate = rr >> 3, unit = rr & 7;
      const unsigned short* Wm = mat ? P.whh1 : P.wih1;
      const unsigned short* src =
          Wm + (size_t)(gate * 1024 + u0 + unit) * 1024 + kc * 32 + lkk * 8;
      *(short8*)&wlds[f * 512 + lane * 8] = *(const short8*)src;
    }
    const int fb = tid >> 2;
    const int jp = tid & 3;
    float creg[2] = {0.f, 0.f};
    float brg[4][2];
    if (tid < 128) {
      creg[0] = P.cell[32768 + fb * 1024 + u0 + 2 * jp];
      creg[1] = P.cell[32768 + fb * 1024 + u0 + 2 * jp + 1];
#pragma unroll
      for (int g = 0; g < 4; ++g) {
        brg[g][0] = P.bsum1[g * 1024 + u0 + 2 * jp];
        brg[g][1] = P.bsum1[g * 1024 + u0 + 2 * jp + 1];
      }
    }
    __syncthreads();

    for (int i = 1; i <= 128; ++i) {
      if (tid < 12) {
        if (tid < 4) poll_ge(&P.arr0[tid * 256], (unsigned)(16 * i));
        else if (i > 1) poll_ge(&P.arr1[(tid - 4) * 256], (unsigned)(16 * (i - 1)));
      }
      __syncthreads();   // all lanes held until polls complete

      f32x4 accA = {0.f, 0.f, 0.f, 0.f}, accB = {0.f, 0.f, 0.f, 0.f};
      const unsigned short* a0p =
          P.h0hist + (size_t)i * 32768 + (size_t)(m * 16 + lr) * 1024 + lkk * 8;
      size_t h1s = (i == 1) ? 1024 : 131072;
      const unsigned short* h1b =
          (i == 1) ? P.h1init : (P.outb + (size_t)(i - 2) * 1024);
      const unsigned short* a1p = h1b + (size_t)(m * 16 + lr) * h1s + lkk * 8;
#pragma unroll
      for (int g4 = 0; g4 < 4; ++g4) {
        short8 a0[8], a1[8];
#pragma unroll
        for (int q = 0; q < 8; ++q) {
          a0[q] = *(const short8*)(a0p + (g4 * 8 + q) * 32);
          a1[q] = *(const short8*)(a1p + (g4 * 8 + q) * 32);
        }
#pragma unroll
        for (int q = 0; q < 8; ++q) {
          int kc = g4 * 8 + q;
          short8 bi = *(const short8*)&wlds[(n * 32 + kc) * 512 + lane * 8];
          short8 bh = *(const short8*)&wlds[(64 + n * 32 + kc) * 512 + lane * 8];
          accA = MFMA16(a0[q], bi, accA);
          accB = MFMA16(a1[q], bh, accB);
        }
      }
      f32x4 acc = accA + accB;
#pragma unroll
      for (int j = 0; j < 4; ++j)
        zbuf[m * 16 + lkk * 4 + j][n * 16 + lr] = acc[j];
      __syncthreads();

      if (tid < 128) {
        unsigned hv = 0;
#pragma unroll
        for (int u = 0; u < 2; ++u) {
          int j = 2 * jp + u;
          float zi = zbuf[fb][j]      + brg[0][u];
          float zf = zbuf[fb][8 + j]  + brg[1][u];
          float zg = zbuf[fb][16 + j] + brg[2][u];
          float zo = zbuf[fb][24 + j] + brg[3][u];
          float ii = 1.f / (1.f + __expf(-zi));
          float ff = 1.f / (1.f + __expf(-zf));
          float gg = tanhf(zg);
          float oo = 1.f / (1.f + __expf(-zo));
          float cn = ff * creg[u] + ii * gg;
          creg[u] = cn;
          float hn = oo * tanhf(cn);
          hv |= ((unsigned)f2bf(hn)) << (16 * u);
        }
        st_u32_dev((unsigned*)&P.outb[(size_t)fb * 131072 + (size_t)(i - 1) * 1024 + u0 + 2 * jp], hv);
      }

      __syncthreads();   // drain outb stores
      if (tid == 0) arrive(&P.arr1[grp * 256]);
    }
  }
}

// ---------------------------------------------------------------------------

extern "C" void kernel_launch(void* const* d_in, const int* in_sizes, int n_in,
                              void* d_out, int out_size, void* d_ws, size_t ws_size,
                              hipStream_t stream) {
  const int*   x      = (const int*)d_in[0];
  const float* hidden = (const float*)d_in[1];
  const float* cell   = (const float*)d_in[2];
  const int*   target = (const int*)d_in[3];
  const float* emb    = (const float*)d_in[5];
  const float* w_ih   = (const float*)d_in[6];
  const float* w_hh   = (const float*)d_in[7];
  const float* b_ih   = (const float*)d_in[8];
  const float* b_hh   = (const float*)d_in[9];
  float* out = (float*)d_out;
  char* ws = (char*)d_ws;

  // ws layout (bytes)
  unsigned short* emb_bf  = (unsigned short*)(ws);                 // 65,536,000
  unsigned short* wih0_bf = (unsigned short*)(ws + 65536000);      //  8,388,608
  unsigned short* whh_bf  = (unsigned short*)(ws + 73924608);      // 16,777,216
  unsigned short* wih1_bf = (unsigned short*)(ws + 90701824);      //  8,388,608
  float*          bsum    = (float*)(ws + 99090432);               //     32,768
  unsigned short* outb    = (unsigned short*)(ws + 99123200);      //  8,388,608
  unsigned int*   barmem  = (unsigned int*)(ws + 107511808);       //     16,384
  // Large transients in d_out's dead space (proj GEMM overwrites last):
  float*          zx0    = (float*)((char*)d_out);                         // 67,108,864
  unsigned short* xseq   = (unsigned short*)((char*)d_out + 67108864);     //  8,388,608
  unsigned short* h0hist = (unsigned short*)((char*)d_out + 75497472);     //  8,454,144
  unsigned short* h1init = (unsigned short*)((char*)d_out + 83951616);     //     65,536

  hipMemsetAsync(barmem, 0, 16384, stream);
  cvt_bf16_k<<<2048, 256, 0, stream>>>(emb, emb_bf, 8192000);
  cvt_bf16_k<<<1024, 256, 0, stream>>>(w_ih, wih0_bf, 1048576);
  cvt_bf16_k<<<2048, 256, 0, stream>>>(w_hh, whh_bf, 2097152);
  cvt_bf16_k<<<1024, 256, 0, stream>>>(w_ih + 4194304, wih1_bf, 1048576);
  cvt_bf16_k<<<32, 256, 0, stream>>>(hidden, h0hist, 8192);          // h0hist[0]
  cvt_bf16_k<<<32, 256, 0, stream>>>(hidden + 32768, h1init, 8192);
  bias_sum_k<<<32, 256, 0, stream>>>(b_ih, b_hh, bsum, 8192);
  embed_k<<<4096, 256, 0, stream>>>(x, target, emb, xseq);

  // Zx0 = x_seq @ w_ih[0]^T + bsum0   [4096 x 4096], 1024 WGs (XCD map)
  gemm_bf16_k<<<1024, 256, 0, stream>>>(xseq, wih0_bf, zx0, bsum, 4096);

  // persistent recurrence (round 12: fence-free cacheable protocol)
  PParams pp;
  pp.zx0 = zx0;
  pp.whh0 = whh_bf;
  pp.wih1 = wih1_bf;
  pp.whh1 = whh_bf + 4194304;
  pp.bsum1 = bsum + 4096;
  pp.cell = cell;
  pp.h0hist = h0hist;
  pp.h1init = h1init;
  pp.outb = outb;
  pp.arr0 = barmem;                // 4 counters, 1KB apart
  pp.arr1 = barmem + 4 * 256;      // 8 counters, 1KB apart
  lstm_persist_k<<<192, 256, 0, stream>>>(pp);

  // out = outb @ emb_bf^T   [4096 x 32000], 8000 WGs (XCD map)
  gemm_bf16_k<<<8000, 256, 0, stream>>>(outb, emb_bf, out, nullptr, 32000);
}